// Round 1
// baseline (1085.547 us; speedup 1.0000x reference)
//
#include <hip/hip_runtime.h>
#include <hip/hip_bf16.h>

// Problem constants (from reference setup_inputs)
#define Bq 2
#define Tq 2048
#define Cq 1024
#define Hq 16
#define HKVq 4
#define HDq 64
#define Gq 4
#define WSq 1024
#define GATE_CHq 32

// ---------------------------------------------------------------------------
// Generic f32 GEMM body: C[M,N] = A[M,K] @ B[K,N], row-major, 128x128 tile,
// BK=8, 256 threads, 8x8 micro-tile per thread, register-prefetch pipeline.
// All dims assumed divisible (M=4096, K=1024, N in {256,1024}).
// ---------------------------------------------------------------------------
__device__ __forceinline__ void gemm_body(
    const float* __restrict__ A, const float* __restrict__ Bp,
    float* __restrict__ Cp, int N, int K, int bm0, int bn0,
    float (*As)[128], float (*Bs)[128]) {
  const int tid = threadIdx.x;
  const int tm = tid >> 4;          // 0..15
  const int tn = tid & 15;          // 0..15
  const int ar = tid >> 1;          // 0..127 (A tile row)
  const int ac = (tid & 1) * 4;     // 0 or 4  (A tile col)
  const int br = tid >> 5;          // 0..7    (B tile row)
  const int bc = (tid & 31) * 4;    // 0..124  (B tile col)

  const float* Aptr = A + (long)(bm0 + ar) * K + ac;
  const float* Bptr = Bp + (long)br * N + bn0 + bc;

  float acc[8][8];
#pragma unroll
  for (int i = 0; i < 8; i++)
#pragma unroll
    for (int j = 0; j < 8; j++) acc[i][j] = 0.f;

  // prefetch first tiles
  float4 av = *(const float4*)(Aptr);
  float4 bv = *(const float4*)(Bptr);

  for (int k0 = 0; k0 < K; k0 += 8) {
    __syncthreads();  // previous iteration's LDS reads done
    As[ac + 0][ar] = av.x;
    As[ac + 1][ar] = av.y;
    As[ac + 2][ar] = av.z;
    As[ac + 3][ar] = av.w;
    *(float4*)&Bs[br][bc] = bv;
    __syncthreads();
    if (k0 + 8 < K) {  // issue next tile loads early; latency hidden by FMAs
      av = *(const float4*)(Aptr + k0 + 8);
      bv = *(const float4*)(Bptr + (long)(k0 + 8) * N);
    }
#pragma unroll
    for (int kk = 0; kk < 8; kk++) {
      float a[8], b[8];
      *(float4*)(a + 0) = *(const float4*)&As[kk][tm * 8];
      *(float4*)(a + 4) = *(const float4*)&As[kk][tm * 8 + 4];
      *(float4*)(b + 0) = *(const float4*)&Bs[kk][tn * 8];
      *(float4*)(b + 4) = *(const float4*)&Bs[kk][tn * 8 + 4];
#pragma unroll
      for (int i = 0; i < 8; i++)
#pragma unroll
        for (int j = 0; j < 8; j++) acc[i][j] += a[i] * b[j];
    }
  }

#pragma unroll
  for (int i = 0; i < 8; i++) {
    float4 lo, hi;
    lo.x = acc[i][0]; lo.y = acc[i][1]; lo.z = acc[i][2]; lo.w = acc[i][3];
    hi.x = acc[i][4]; hi.y = acc[i][5]; hi.z = acc[i][6]; hi.w = acc[i][7];
    float* crow = Cp + (long)(bm0 + tm * 8 + i) * N + bn0 + tn * 8;
    *(float4*)(crow) = lo;
    *(float4*)(crow + 4) = hi;
  }
}

// Fused QKV projection: grid (12, 32). bx<8 -> Q (N=1024), 8..9 -> K, 10..11 -> V.
__global__ __launch_bounds__(256) void qkv_gemm(
    const float* __restrict__ x, const float* __restrict__ Wq,
    const float* __restrict__ Wk, const float* __restrict__ Wv,
    float* __restrict__ Q, float* __restrict__ Kk, float* __restrict__ Vv) {
  __shared__ float As[8][128];
  __shared__ float Bs[8][128];
  int bx = blockIdx.x, by = blockIdx.y;
  const float* Bp;
  float* Cp;
  int N, nb;
  if (bx < 8)       { Bp = Wq; Cp = Q;  N = 1024; nb = bx; }
  else if (bx < 10) { Bp = Wk; Cp = Kk; N = 256;  nb = bx - 8; }
  else              { Bp = Wv; Cp = Vv; N = 256;  nb = bx - 10; }
  gemm_body(x, Bp, Cp, N, Cq, by * 128, nb * 128, As, Bs);
}

__global__ __launch_bounds__(256) void sgemm_kernel(
    const float* __restrict__ A, const float* __restrict__ B,
    float* __restrict__ C, int N, int K) {
  __shared__ float As[8][128];
  __shared__ float Bs[8][128];
  gemm_body(A, B, C, N, K, blockIdx.y * 128, blockIdx.x * 128, As, Bs);
}

// ---------------------------------------------------------------------------
// Postprocess: gate + ve into V; RoPE + RMSNorm on Q and K.
// grid = B*T blocks, 256 threads. wave w (0..3) handles kv-head w and q-heads
// {w, 4+w, 8+w, 12+w}. lane = element dim (64 = one wave per head vector).
// ---------------------------------------------------------------------------
__device__ __forceinline__ float rope_rms(float u, int lane, int t,
                                          const float* __restrict__ cosp,
                                          const float* __restrict__ sinp) {
  int i = lane & 31;
  float c = cosp[t * 32 + i];
  float s = sinp[t * 32 + i];
  float up = __shfl_xor(u, 32);  // partner half
  float r = (lane < 32) ? (u * c + up * s) : (u * c - up * s);
  float sum = r * r;
#pragma unroll
  for (int off = 32; off >= 1; off >>= 1) sum += __shfl_xor(sum, off);
  return r * rsqrtf(sum * (1.f / 64.f) + 1.1920928955078125e-07f);
}

__global__ __launch_bounds__(256) void postproc(
    const float* __restrict__ x, const float* __restrict__ ve,
    const float* __restrict__ cosp, const float* __restrict__ sinp,
    const float* __restrict__ Wg, float* __restrict__ Q,
    float* __restrict__ Kk, float* __restrict__ Vv) {
  int bt = blockIdx.x;          // b*T + t
  int t = bt & (Tq - 1);
  int tid = threadIdx.x;
  int w = tid >> 6;             // wave = kv head
  int lane = tid & 63;

  // gate[w] = 2*sigmoid(dot(x[bt, :32], Wg[:, w]))
  float pg = 0.f;
  if (lane < 32) pg = x[(long)bt * Cq + lane] * Wg[lane * HKVq + w];
#pragma unroll
  for (int off = 16; off >= 1; off >>= 1) pg += __shfl_xor(pg, off);
  float z = __shfl(pg, 0);
  float gate = 2.f / (1.f + expf(-z));

  // v += gate * ve
  long vi = (long)bt * (HKVq * HDq) + w * HDq + lane;
  Vv[vi] += gate * ve[vi];

  // K: rope + rms
  {
    float u = Kk[vi];
    Kk[vi] = rope_rms(u, lane, t, cosp, sinp);
  }
  // Q: 4 heads per wave
#pragma unroll
  for (int hi = 0; hi < 4; hi++) {
    int h = hi * 4 + w;
    long qi = (long)bt * (Hq * HDq) + h * HDq + lane;
    float u = Q[qi];
    Q[qi] = rope_rms(u, lane, t, cosp, sinp);
  }
}

// ---------------------------------------------------------------------------
// Sliding-window GQA attention, f32, flash-style online softmax.
// grid = B*HKV*(T/64) = 256 blocks, 256 threads.
// thread = (g = tid/64, qi = tid%64); each wave shares g; K/V rows read from
// LDS at wave-uniform addresses (broadcast, conflict-free).
// ---------------------------------------------------------------------------
__global__ __launch_bounds__(256) void attn(
    const float* __restrict__ Q, const float* __restrict__ Kk,
    const float* __restrict__ Vv, float* __restrict__ Y) {
  __shared__ float Ks[64][64];
  __shared__ float Vs[64][64];

  int blk = blockIdx.x;
  int qt = blk & 31;
  int hkv = (blk >> 5) & 3;
  int b = blk >> 7;

  int tid = threadIdx.x;
  int g = tid >> 6;
  int qi = tid & 63;
  int h = hkv * Gq + g;
  int qpos = qt * 64 + qi;

  const float4* qptr =
      (const float4*)(Q + ((long)(b * Tq + qpos) * Hq + h) * HDq);
  float4 qv[16];
#pragma unroll
  for (int i = 0; i < 16; i++) qv[i] = qptr[i];

  float4 ov[16];
#pragma unroll
  for (int i = 0; i < 16; i++) { ov[i].x = 0.f; ov[i].y = 0.f; ov[i].z = 0.f; ov[i].w = 0.f; }
  float m = -1e30f, l = 0.f;

  int kbeg = qt * 64 - (WSq - 1);
  if (kbeg < 0) kbeg = 0;
  kbeg &= ~63;
  int kend = qt * 64;  // last tile start (covers diagonal)

  // cooperative load indices: 4 lanes per row, fully-coalesced 64B per quad
  int lr = tid >> 2;            // 0..63 tile row
  int lc = (tid & 3) * 4;       // col offset (float4 # j adds 16 floats)

  for (int k0 = kbeg; k0 <= kend; k0 += 64) {
    const float* kgb = Kk + ((long)(b * Tq + k0 + lr) * HKVq + hkv) * HDq;
    const float* vgb = Vv + ((long)(b * Tq + k0 + lr) * HKVq + hkv) * HDq;
    __syncthreads();
#pragma unroll
    for (int j = 0; j < 4; j++) {
      *(float4*)&Ks[lr][lc + 16 * j] = *(const float4*)(kgb + lc + 16 * j);
      *(float4*)&Vs[lr][lc + 16 * j] = *(const float4*)(vgb + lc + 16 * j);
    }
    __syncthreads();

#pragma unroll 4
    for (int kk = 0; kk < 64; kk++) {
      int kpos = k0 + kk;
      bool valid = (kpos <= qpos) && (kpos > qpos - WSq);
      const float4* kr = (const float4*)&Ks[kk][0];
      float4 acc;
      acc.x = 0.f; acc.y = 0.f; acc.z = 0.f; acc.w = 0.f;
#pragma unroll
      for (int i = 0; i < 16; i++) {
        float4 kv4 = kr[i];
        acc.x += qv[i].x * kv4.x;
        acc.y += qv[i].y * kv4.y;
        acc.z += qv[i].z * kv4.z;
        acc.w += qv[i].w * kv4.w;
      }
      float sdot = (acc.x + acc.y) + (acc.z + acc.w);
      float s = valid ? sdot * 0.125f : -1e30f;
      if (s > m) {  // rare after warmup; rescale running state
        float alpha = expf(m - s);
        l *= alpha;
#pragma unroll
        for (int i = 0; i < 16; i++) {
          ov[i].x *= alpha; ov[i].y *= alpha; ov[i].z *= alpha; ov[i].w *= alpha;
        }
        m = s;
      }
      float p = valid ? expf(s - m) : 0.f;
      l += p;
      const float4* vr = (const float4*)&Vs[kk][0];
#pragma unroll
      for (int i = 0; i < 16; i++) {
        float4 vv4 = vr[i];
        ov[i].x += p * vv4.x;
        ov[i].y += p * vv4.y;
        ov[i].z += p * vv4.z;
        ov[i].w += p * vv4.w;
      }
    }
  }

  float inv = 1.f / l;
  float4* yp = (float4*)(Y + ((long)(b * Tq + qpos) * Hq + h) * HDq);
#pragma unroll
  for (int i = 0; i < 16; i++) {
    float4 o = ov[i];
    o.x *= inv; o.y *= inv; o.z *= inv; o.w *= inv;
    yp[i] = o;
  }
}

// ---------------------------------------------------------------------------
extern "C" void kernel_launch(void* const* d_in, const int* in_sizes, int n_in,
                              void* d_out, int out_size, void* d_ws,
                              size_t ws_size, hipStream_t stream) {
  const float* x     = (const float*)d_in[0];
  const float* ve    = (const float*)d_in[1];
  const float* cosp  = (const float*)d_in[2];
  const float* sinp  = (const float*)d_in[3];
  const float* Wq    = (const float*)d_in[4];
  const float* Wk    = (const float*)d_in[5];
  const float* Wv    = (const float*)d_in[6];
  const float* Wproj = (const float*)d_in[7];
  const float* Wg    = (const float*)d_in[8];
  // d_in[9] = ws scalar; window hardcoded (WSq=1024) per setup_inputs.

  // workspace: Q(16MB) K(4MB) V(4MB) Y(16MB) = 40MB
  float* Q  = (float*)d_ws;
  float* Kk = Q + (long)Bq * Tq * Hq * HDq;          // +4194304
  float* Vv = Kk + (long)Bq * Tq * HKVq * HDq;       // +1048576
  float* Y  = Vv + (long)Bq * Tq * HKVq * HDq;       // +1048576
  float* out = (float*)d_out;

  qkv_gemm<<<dim3(12, 32), 256, 0, stream>>>(x, Wq, Wk, Wv, Q, Kk, Vv);
  postproc<<<Bq * Tq, 256, 0, stream>>>(x, ve, cosp, sinp, Wg, Q, Kk, Vv);
  attn<<<Bq * HKVq * (Tq / 64), 256, 0, stream>>>(Q, Kk, Vv, Y);
  sgemm_kernel<<<dim3(8, 32), 256, 0, stream>>>(Y, Wproj, out, Cq, Cq);
}

// Round 2
// 498.494 us; speedup vs baseline: 2.1777x; 2.1777x over previous
//
#include <hip/hip_runtime.h>
#include <hip/hip_bf16.h>

// Problem constants (from reference setup_inputs)
#define Bq 2
#define Tq 2048
#define Cq 1024
#define Hq 16
#define HKVq 4
#define HDq 64
#define Gq 4
#define WSq 1024
#define GATE_CHq 32

typedef __attribute__((ext_vector_type(8))) short short8;   // 8 bf16 (4 VGPRs)
typedef __attribute__((ext_vector_type(4))) float f32x4;    // MFMA C/D frag

__device__ __forceinline__ unsigned short f2bf(float f) {
  unsigned int u = __float_as_uint(f);
  unsigned int r = (u + 0x7FFFu + ((u >> 16) & 1u)) >> 16;  // RNE
  return (unsigned short)r;
}

// ---------------------------------------------------------------------------
// f32 GEMM body (unchanged from round 1): 128x128 tile, BK=8, 8x8/thread.
// ---------------------------------------------------------------------------
__device__ __forceinline__ void gemm_body(
    const float* __restrict__ A, const float* __restrict__ Bp,
    float* __restrict__ Cp, int N, int K, int bm0, int bn0,
    float (*As)[128], float (*Bs)[128]) {
  const int tid = threadIdx.x;
  const int tm = tid >> 4;
  const int tn = tid & 15;
  const int ar = tid >> 1;
  const int ac = (tid & 1) * 4;
  const int br = tid >> 5;
  const int bc = (tid & 31) * 4;

  const float* Aptr = A + (long)(bm0 + ar) * K + ac;
  const float* Bptr = Bp + (long)br * N + bn0 + bc;

  float acc[8][8];
#pragma unroll
  for (int i = 0; i < 8; i++)
#pragma unroll
    for (int j = 0; j < 8; j++) acc[i][j] = 0.f;

  float4 av = *(const float4*)(Aptr);
  float4 bv = *(const float4*)(Bptr);

  for (int k0 = 0; k0 < K; k0 += 8) {
    __syncthreads();
    As[ac + 0][ar] = av.x;
    As[ac + 1][ar] = av.y;
    As[ac + 2][ar] = av.z;
    As[ac + 3][ar] = av.w;
    *(float4*)&Bs[br][bc] = bv;
    __syncthreads();
    if (k0 + 8 < K) {
      av = *(const float4*)(Aptr + k0 + 8);
      bv = *(const float4*)(Bptr + (long)(k0 + 8) * N);
    }
#pragma unroll
    for (int kk = 0; kk < 8; kk++) {
      float a[8], b[8];
      *(float4*)(a + 0) = *(const float4*)&As[kk][tm * 8];
      *(float4*)(a + 4) = *(const float4*)&As[kk][tm * 8 + 4];
      *(float4*)(b + 0) = *(const float4*)&Bs[kk][tn * 8];
      *(float4*)(b + 4) = *(const float4*)&Bs[kk][tn * 8 + 4];
#pragma unroll
      for (int i = 0; i < 8; i++)
#pragma unroll
        for (int j = 0; j < 8; j++) acc[i][j] += a[i] * b[j];
    }
  }

#pragma unroll
  for (int i = 0; i < 8; i++) {
    float4 lo, hi;
    lo.x = acc[i][0]; lo.y = acc[i][1]; lo.z = acc[i][2]; lo.w = acc[i][3];
    hi.x = acc[i][4]; hi.y = acc[i][5]; hi.z = acc[i][6]; hi.w = acc[i][7];
    float* crow = Cp + (long)(bm0 + tm * 8 + i) * N + bn0 + tn * 8;
    *(float4*)(crow) = lo;
    *(float4*)(crow + 4) = hi;
  }
}

__global__ __launch_bounds__(256) void qkv_gemm(
    const float* __restrict__ x, const float* __restrict__ Wq,
    const float* __restrict__ Wk, const float* __restrict__ Wv,
    float* __restrict__ Q, float* __restrict__ Kk, float* __restrict__ Vv) {
  __shared__ float As[8][128];
  __shared__ float Bs[8][128];
  int bx = blockIdx.x, by = blockIdx.y;
  const float* Bp;
  float* Cp;
  int N, nb;
  if (bx < 8)       { Bp = Wq; Cp = Q;  N = 1024; nb = bx; }
  else if (bx < 10) { Bp = Wk; Cp = Kk; N = 256;  nb = bx - 8; }
  else              { Bp = Wv; Cp = Vv; N = 256;  nb = bx - 10; }
  gemm_body(x, Bp, Cp, N, Cq, by * 128, nb * 128, As, Bs);
}

__global__ __launch_bounds__(256) void sgemm_kernel(
    const float* __restrict__ A, const float* __restrict__ B,
    float* __restrict__ C, int N, int K) {
  __shared__ float As[8][128];
  __shared__ float Bs[8][128];
  gemm_body(A, B, C, N, K, blockIdx.y * 128, blockIdx.x * 128, As, Bs);
}

// ---------------------------------------------------------------------------
// Postprocess: gate+ve into V; RoPE+RMSNorm on Q,K; emit bf16 buffers:
//   Qb[b][hkv][g][q][d]   (A-frag friendly, contiguous per (hkv,g))
//   Kb[b][hkv][k][d]      (contiguous K tiles)
//   Vtb[b][hkv][d][k]     (transposed so PV B-frags are contiguous)
// ---------------------------------------------------------------------------
__device__ __forceinline__ float rope_rms(float u, int lane, int t,
                                          const float* __restrict__ cosp,
                                          const float* __restrict__ sinp) {
  int i = lane & 31;
  float c = cosp[t * 32 + i];
  float s = sinp[t * 32 + i];
  float up = __shfl_xor(u, 32);
  float r = (lane < 32) ? (u * c + up * s) : (u * c - up * s);
  float sum = r * r;
#pragma unroll
  for (int off = 32; off >= 1; off >>= 1) sum += __shfl_xor(sum, off);
  return r * rsqrtf(sum * (1.f / 64.f) + 1.1920928955078125e-07f);
}

__global__ __launch_bounds__(256) void postproc(
    const float* __restrict__ x, const float* __restrict__ ve,
    const float* __restrict__ cosp, const float* __restrict__ sinp,
    const float* __restrict__ Wg, const float* __restrict__ Qf,
    const float* __restrict__ Kf, const float* __restrict__ Vf,
    unsigned short* __restrict__ Qb, unsigned short* __restrict__ Kb,
    unsigned short* __restrict__ Vtb) {
  int bt = blockIdx.x;          // b*T + t
  int b = bt >> 11;
  int t = bt & (Tq - 1);
  int tid = threadIdx.x;
  int w = tid >> 6;             // kv head
  int lane = tid & 63;

  float pg = 0.f;
  if (lane < 32) pg = x[(long)bt * Cq + lane] * Wg[lane * HKVq + w];
#pragma unroll
  for (int off = 16; off >= 1; off >>= 1) pg += __shfl_xor(pg, off);
  float z = __shfl(pg, 0);
  float gate = 2.f / (1.f + expf(-z));

  long vi = (long)bt * (HKVq * HDq) + w * HDq + lane;
  float v = Vf[vi] + gate * ve[vi];
  Vtb[((long)((b * 4 + w) * 64 + lane)) * Tq + t] = f2bf(v);

  float kv = rope_rms(Kf[vi], lane, t, cosp, sinp);
  Kb[((long)((b * 4 + w) * Tq + t)) * 64 + lane] = f2bf(kv);

#pragma unroll
  for (int hi = 0; hi < 4; hi++) {
    int h = hi * 4 + w;         // hkv = hi, g = w
    float q = rope_rms(Qf[(long)bt * (Hq * HDq) + h * HDq + lane], lane, t,
                       cosp, sinp);
    Qb[((long)(((b * 4 + hi) * 4 + w) * Tq + t)) * 64 + lane] = f2bf(q);
  }
}

// ---------------------------------------------------------------------------
// MFMA flash attention, sliding window 1024.
// Block = (b, hkv, qt of 16 q-positions); 4 waves = 4 GQA heads (g).
// Wave: M=16 rows (q), per 64-key tile: 8 MFMA QK + online softmax +
// P LDS round-trip (C-layout -> A-layout) + 8 MFMA PV.
// K/Vt LDS tiles use granule-XOR swizzle: phys = glog ^ (row&7).
// ---------------------------------------------------------------------------
#define CEXP 0.18033688011112042f  // 0.125 * log2(e)

__global__ __launch_bounds__(256) void attn_mfma(
    const unsigned short* __restrict__ Qb, const unsigned short* __restrict__ Kb,
    const unsigned short* __restrict__ Vtb, float* __restrict__ Y) {
  __shared__ unsigned short Ks[64 * 64];
  __shared__ unsigned short Vts[64 * 64];
  __shared__ float Ps[4 * 16 * 68];   // per-wave 16x68 (stride 68 keeps 16B align)

  int bid = blockIdx.x;
  int qt = bid & 127;
  int hkv = (bid >> 7) & 3;
  int b = bid >> 9;
  int tid = threadIdx.x;
  int g = tid >> 6;
  int lane = tid & 63;
  int quad = lane >> 4;
  int l16 = lane & 15;

  // Q A-frags (m = l16, k = quad*8+j [+32 for frag1]) straight from global
  const unsigned short* qb =
      Qb + ((long)(((b * 4 + hkv) * 4 + g) * Tq + qt * 16 + l16)) * 64 + quad * 8;
  short8 QA0 = *(const short8*)(qb);
  short8 QA1 = *(const short8*)(qb + 32);

  f32x4 O[4];
#pragma unroll
  for (int nt = 0; nt < 4; nt++) O[nt] = (f32x4){0.f, 0.f, 0.f, 0.f};
  float m[4] = {-1e30f, -1e30f, -1e30f, -1e30f};
  float l[4] = {0.f, 0.f, 0.f, 0.f};

  int lo = qt * 16 - (WSq - 1);
  int st = (lo < 0 ? 0 : lo) >> 6;
  int et = (qt * 16 + 15) >> 6;

  const unsigned short* Kbase = Kb + ((long)((b * 4 + hkv) * Tq)) * 64;
  const unsigned short* Vbase = Vtb + ((long)((b * 4 + hkv) * 64)) * Tq;
  float* myPs = Ps + g * 16 * 68;

  for (int kt = st; kt <= et; kt++) {
    int k0 = kt * 64;
    __syncthreads();
    // stage K tile [64 keys][64 d] and Vt tile [64 d][64 keys], swizzled
#pragma unroll
    for (int c = tid; c < 512; c += 256) {
      int row = c >> 3, gl = c & 7;
      *(uint4*)(&Ks[row * 64 + ((gl ^ (row & 7)) * 8)]) =
          *(const uint4*)(Kbase + ((long)(k0 + row)) * 64 + gl * 8);
      *(uint4*)(&Vts[row * 64 + ((gl ^ (row & 7)) * 8)]) =
          *(const uint4*)(Vbase + (long)row * Tq + k0 + gl * 8);
    }
    __syncthreads();

    // S = Q K^T  (per wave: M=16, N=64)
    f32x4 S4[4];
#pragma unroll
    for (int nt = 0; nt < 4; nt++) {
      int key = nt * 16 + l16;
      short8 kb0 = *(const short8*)(&Ks[key * 64 + ((quad ^ (key & 7)) * 8)]);
      short8 kb1 = *(const short8*)(&Ks[key * 64 + (((quad + 4) ^ (key & 7)) * 8)]);
      f32x4 acc = (f32x4){0.f, 0.f, 0.f, 0.f};
      acc = __builtin_amdgcn_mfma_f32_16x16x32_bf16(QA0, kb0, acc, 0, 0, 0);
      acc = __builtin_amdgcn_mfma_f32_16x16x32_bf16(QA1, kb1, acc, 0, 0, 0);
      S4[nt] = acc;
    }

    // mask + row max (rows live at quad*4+r; cols at nt*16+l16)
    float Sv[4][4];
    float rm[4] = {-1e30f, -1e30f, -1e30f, -1e30f};
#pragma unroll
    for (int nt = 0; nt < 4; nt++) {
      int kpos = k0 + nt * 16 + l16;
#pragma unroll
      for (int r = 0; r < 4; r++) {
        int qpos = qt * 16 + quad * 4 + r;
        bool valid = (kpos <= qpos) && (kpos >= qpos - (WSq - 1));
        float s = valid ? S4[nt][r] : -1e30f;
        Sv[nt][r] = s;
        rm[r] = fmaxf(rm[r], s);
      }
    }
#pragma unroll
    for (int r = 0; r < 4; r++) {
      float v = rm[r];
      v = fmaxf(v, __shfl_xor(v, 1));
      v = fmaxf(v, __shfl_xor(v, 2));
      v = fmaxf(v, __shfl_xor(v, 4));
      v = fmaxf(v, __shfl_xor(v, 8));
      rm[r] = v;
    }
    float al[4], rs[4];
#pragma unroll
    for (int r = 0; r < 4; r++) {
      float mn = fmaxf(m[r], rm[r]);
      al[r] = exp2f((m[r] - mn) * CEXP);
      m[r] = mn;
      rs[r] = 0.f;
    }
    float Pv[4][4];
#pragma unroll
    for (int nt = 0; nt < 4; nt++) {
#pragma unroll
      for (int r = 0; r < 4; r++) {
        float s = Sv[nt][r];
        float p = (s > -5e29f) ? exp2f((s - m[r]) * CEXP) : 0.f;
        Pv[nt][r] = p;
        rs[r] += p;
      }
    }
#pragma unroll
    for (int r = 0; r < 4; r++) {
      float v = rs[r];
      v += __shfl_xor(v, 1);
      v += __shfl_xor(v, 2);
      v += __shfl_xor(v, 4);
      v += __shfl_xor(v, 8);
      l[r] = l[r] * al[r] + v;
    }
#pragma unroll
    for (int nt = 0; nt < 4; nt++)
#pragma unroll
      for (int r = 0; r < 4; r++) O[nt][r] *= al[r];

    // P: C-layout -> LDS -> A-layout (bf16)
#pragma unroll
    for (int nt = 0; nt < 4; nt++)
#pragma unroll
      for (int r = 0; r < 4; r++)
        myPs[(quad * 4 + r) * 68 + nt * 16 + l16] = Pv[nt][r];

    const float* prow = myPs + l16 * 68;
    f32x4 a0 = *(const f32x4*)(prow + quad * 8);
    f32x4 a1 = *(const f32x4*)(prow + quad * 8 + 4);
    f32x4 b0 = *(const f32x4*)(prow + 32 + quad * 8);
    f32x4 b1 = *(const f32x4*)(prow + 32 + quad * 8 + 4);
    union { short8 s; unsigned short u[8]; } pa0, pa1;
#pragma unroll
    for (int j = 0; j < 4; j++) {
      pa0.u[j] = f2bf(a0[j]);
      pa0.u[4 + j] = f2bf(a1[j]);
      pa1.u[j] = f2bf(b0[j]);
      pa1.u[4 + j] = f2bf(b1[j]);
    }

    // O += P V  (B-frags from transposed V tile; n = nt*16+l16 = dim d)
#pragma unroll
    for (int nt = 0; nt < 4; nt++) {
      int d = nt * 16 + l16;
      short8 vb0 = *(const short8*)(&Vts[d * 64 + ((quad ^ (l16 & 7)) * 8)]);
      short8 vb1 = *(const short8*)(&Vts[d * 64 + (((quad + 4) ^ (l16 & 7)) * 8)]);
      O[nt] = __builtin_amdgcn_mfma_f32_16x16x32_bf16(pa0.s, vb0, O[nt], 0, 0, 0);
      O[nt] = __builtin_amdgcn_mfma_f32_16x16x32_bf16(pa1.s, vb1, O[nt], 0, 0, 0);
    }
  }

  float inv[4];
#pragma unroll
  for (int r = 0; r < 4; r++) inv[r] = 1.f / l[r];
  int h = hkv * 4 + g;
#pragma unroll
  for (int nt = 0; nt < 4; nt++)
#pragma unroll
    for (int r = 0; r < 4; r++)
      Y[((long)(b * Tq + qt * 16 + quad * 4 + r)) * (Hq * HDq) + h * 64 +
        nt * 16 + l16] = O[nt][r] * inv[r];
}

// ---------------------------------------------------------------------------
extern "C" void kernel_launch(void* const* d_in, const int* in_sizes, int n_in,
                              void* d_out, int out_size, void* d_ws,
                              size_t ws_size, hipStream_t stream) {
  const float* x     = (const float*)d_in[0];
  const float* ve    = (const float*)d_in[1];
  const float* cosp  = (const float*)d_in[2];
  const float* sinp  = (const float*)d_in[3];
  const float* Wq    = (const float*)d_in[4];
  const float* Wk    = (const float*)d_in[5];
  const float* Wv    = (const float*)d_in[6];
  const float* Wproj = (const float*)d_in[7];
  const float* Wg    = (const float*)d_in[8];

  // workspace layout (36 MB):
  //   Qf (f32, 16MB) — aliased as Y after postproc consumes it
  //   Kf (f32, 4MB), Vf (f32, 4MB)
  //   Qb (bf16, 8MB), Kb (bf16, 2MB), Vtb (bf16, 2MB)
  float* Qf = (float*)d_ws;
  float* Kf = Qf + (long)Bq * Tq * Hq * HDq;           // +4,194,304
  float* Vf = Kf + (long)Bq * Tq * HKVq * HDq;         // +1,048,576
  unsigned short* Qbb = (unsigned short*)(Vf + (long)Bq * Tq * HKVq * HDq);
  unsigned short* Kbb = Qbb + (long)Bq * Tq * Hq * HDq;
  unsigned short* Vtb = Kbb + (long)Bq * Tq * HKVq * HDq;
  float* Y = Qf;  // Qf dead after postproc
  float* out = (float*)d_out;

  qkv_gemm<<<dim3(12, 32), 256, 0, stream>>>(x, Wq, Wk, Wv, Qf, Kf, Vf);
  postproc<<<Bq * Tq, 256, 0, stream>>>(x, ve, cosp, sinp, Wg, Qf, Kf, Vf,
                                        Qbb, Kbb, Vtb);
  attn_mfma<<<Bq * HKVq * (Tq / 16), 256, 0, stream>>>(Qbb, Kbb, Vtb, Y);
  sgemm_kernel<<<dim3(8, 32), 256, 0, stream>>>(Y, Wproj, out, Cq, Cq);
}

// Round 3
// 243.670 us; speedup vs baseline: 4.4550x; 2.0458x over previous
//
#include <hip/hip_runtime.h>
#include <hip/hip_bf16.h>

// Problem constants
#define Bq 2
#define Tq 2048
#define Cq 1024
#define Hq 16
#define HKVq 4
#define HDq 64
#define Gq 4
#define WSq 1024
#define GATE_CHq 32

typedef __attribute__((ext_vector_type(8))) short short8;   // 8 bf16 (4 VGPRs)
typedef __attribute__((ext_vector_type(4))) float f32x4;    // MFMA C/D frag
typedef unsigned int u32;

__device__ __forceinline__ unsigned short f2bf(float f) {
  unsigned int u = __float_as_uint(f);
  unsigned int r = (u + 0x7FFFu + ((u >> 16) & 1u)) >> 16;  // RNE
  return (unsigned short)r;
}

__device__ __forceinline__ void gl_lds16(const unsigned short* g,
                                         unsigned short* l) {
  __builtin_amdgcn_global_load_lds(
      (const u32 __attribute__((address_space(1)))*)g,
      (u32 __attribute__((address_space(3)))*)l, 16, 0, 0);
}

// ---------------------------------------------------------------------------
// bf16 MFMA GEMM: C[M][N] (f32) = A[M][K] @ Bt[N][K]^T.
// 128x128 tile, BK=32, 256 threads (4 waves, 64x64 each), global_load_lds
// staging with granule-XOR swizzle (phys = glog ^ ((m>>1)&3)) so all frag
// ds_read_b128s are 2-way (free). M%128==0, N%128==0, K%32==0.
// ---------------------------------------------------------------------------
__global__ __launch_bounds__(256) void gemm_bt(
    const unsigned short* __restrict__ A, const unsigned short* __restrict__ Bt,
    float* __restrict__ C, int M, int N, int K) {
  __shared__ __attribute__((aligned(16))) unsigned short As[128 * 32];
  __shared__ __attribute__((aligned(16))) unsigned short Bs[128 * 32];

  const int bm0 = blockIdx.y * 128, bn0 = blockIdx.x * 128;
  const int tid = threadIdx.x;
  const int w = tid >> 6, lane = tid & 63;
  const int wm = (w >> 1) * 64, wn = (w & 1) * 64;
  const int quad = lane >> 4, l16 = lane & 15;

  f32x4 acc[4][4];
#pragma unroll
  for (int mt = 0; mt < 4; mt++)
#pragma unroll
    for (int nt = 0; nt < 4; nt++) acc[mt][nt] = (f32x4){0.f, 0.f, 0.f, 0.f};

  // staging: slot s = issue*256 + tid; LDS gets 16B at slot*16; global source
  // granule is XOR-swizzled so frag reads are conflict-free.
  int goff[2];
#pragma unroll
  for (int i = 0; i < 2; i++) {
    int s = i * 256 + tid;
    int m = s >> 2, gp = s & 3;
    int gl = gp ^ ((m >> 1) & 3);
    goff[i] = m * K + gl * 8;
  }
  const unsigned short* Ab = A + (long)bm0 * K;
  const unsigned short* Bb = Bt + (long)bn0 * K;

  // frag LDS pointers (fixed): slot = m_local*4 + (quad ^ ((m_local>>1)&3))
  const unsigned short* pA[4];
  const unsigned short* pB[4];
#pragma unroll
  for (int t = 0; t < 4; t++) {
    int ml = wm + t * 16 + l16;
    pA[t] = &As[(ml * 4 + (quad ^ ((ml >> 1) & 3))) * 8];
    int nl = wn + t * 16 + l16;
    pB[t] = &Bs[(nl * 4 + (quad ^ ((nl >> 1) & 3))) * 8];
  }

  for (int k0 = 0; k0 < K; k0 += 32) {
    __syncthreads();
#pragma unroll
    for (int i = 0; i < 2; i++) {
      gl_lds16(Ab + goff[i] + k0, &As[(i * 256 + w * 64) * 8]);
      gl_lds16(Bb + goff[i] + k0, &Bs[(i * 256 + w * 64) * 8]);
    }
    __syncthreads();

    short8 af[4], bf[4];
#pragma unroll
    for (int t = 0; t < 4; t++) af[t] = *(const short8*)pA[t];
#pragma unroll
    for (int t = 0; t < 4; t++) bf[t] = *(const short8*)pB[t];
#pragma unroll
    for (int mt = 0; mt < 4; mt++)
#pragma unroll
      for (int nt = 0; nt < 4; nt++)
        acc[mt][nt] = __builtin_amdgcn_mfma_f32_16x16x32_bf16(
            af[mt], bf[nt], acc[mt][nt], 0, 0, 0);
  }

#pragma unroll
  for (int mt = 0; mt < 4; mt++)
#pragma unroll
    for (int nt = 0; nt < 4; nt++) {
      int row0 = bm0 + wm + mt * 16 + quad * 4;
      int col = bn0 + wn + nt * 16 + l16;
#pragma unroll
      for (int r = 0; r < 4; r++)
        C[(long)(row0 + r) * N + col] = acc[mt][nt][r];
    }
}

// ---------------------------------------------------------------------------
// f32 -> bf16 flat cast (n divisible by 2048 per launch config)
// ---------------------------------------------------------------------------
__global__ __launch_bounds__(256) void cast_bf16(
    const float* __restrict__ S, unsigned short* __restrict__ D) {
  int i = (blockIdx.x * 256 + threadIdx.x) * 8;
  float4 a = *(const float4*)(S + i);
  float4 b = *(const float4*)(S + i + 4);
  union { short8 v; unsigned short u[8]; } o;
  o.u[0] = f2bf(a.x); o.u[1] = f2bf(a.y); o.u[2] = f2bf(a.z); o.u[3] = f2bf(a.w);
  o.u[4] = f2bf(b.x); o.u[5] = f2bf(b.y); o.u[6] = f2bf(b.z); o.u[7] = f2bf(b.w);
  *(short8*)(D + i) = o.v;
}

// ---------------------------------------------------------------------------
// Weight transpose + cast: S[1024][N] f32 -> D[N][1024] bf16 (64x64 LDS tiles)
// ---------------------------------------------------------------------------
__global__ __launch_bounds__(256) void wtrans(
    const float* __restrict__ S, unsigned short* __restrict__ D, int N) {
  __shared__ float tile[64][65];
  int n0 = blockIdx.x * 64, k0 = blockIdx.y * 64;
  int tid = threadIdx.x;
#pragma unroll
  for (int i = 0; i < 16; i++) {
    int idx = i * 256 + tid;
    int kl = idx >> 6, nl = idx & 63;
    tile[kl][nl] = S[(long)(k0 + kl) * N + n0 + nl];
  }
  __syncthreads();
#pragma unroll
  for (int i = 0; i < 16; i++) {
    int idx = i * 256 + tid;
    int nl = idx >> 6, kl = idx & 63;
    D[(long)(n0 + nl) * 1024 + k0 + kl] = f2bf(tile[kl][nl]);
  }
}

// ---------------------------------------------------------------------------
// Postprocess: gate+ve into V; RoPE+RMSNorm on Q,K; emit bf16:
//   Qb[b][hkv][g][q][d], Kb[b][hkv][k][d], Vtb[b][hkv][d][k]
// Reads fused QKV f32 [B*T][1536] (q 0:1024 | k 1024:1280 | v 1280:1536).
// ---------------------------------------------------------------------------
__device__ __forceinline__ float rope_rms(float u, int lane, int t,
                                          const float* __restrict__ cosp,
                                          const float* __restrict__ sinp) {
  int i = lane & 31;
  float c = cosp[t * 32 + i];
  float s = sinp[t * 32 + i];
  float up = __shfl_xor(u, 32);
  float r = (lane < 32) ? (u * c + up * s) : (u * c - up * s);
  float sum = r * r;
#pragma unroll
  for (int off = 32; off >= 1; off >>= 1) sum += __shfl_xor(sum, off);
  return r * rsqrtf(sum * (1.f / 64.f) + 1.1920928955078125e-07f);
}

__global__ __launch_bounds__(256) void postproc(
    const float* __restrict__ x, const float* __restrict__ ve,
    const float* __restrict__ cosp, const float* __restrict__ sinp,
    const float* __restrict__ Wg, const float* __restrict__ QKV,
    unsigned short* __restrict__ Qb, unsigned short* __restrict__ Kb,
    unsigned short* __restrict__ Vtb) {
  int bt = blockIdx.x;          // b*T + t
  int b = bt >> 11;
  int t = bt & (Tq - 1);
  int tid = threadIdx.x;
  int w = tid >> 6;             // kv head
  int lane = tid & 63;
  const float* row = QKV + (long)bt * 1536;

  float pg = 0.f;
  if (lane < 32) pg = x[(long)bt * Cq + lane] * Wg[lane * HKVq + w];
#pragma unroll
  for (int off = 16; off >= 1; off >>= 1) pg += __shfl_xor(pg, off);
  float z = __shfl(pg, 0);
  float gate = 2.f / (1.f + expf(-z));

  long vi = (long)bt * (HKVq * HDq) + w * HDq + lane;
  float v = row[1280 + w * HDq + lane] + gate * ve[vi];
  Vtb[((long)((b * 4 + w) * 64 + lane)) * Tq + t] = f2bf(v);

  float kv = rope_rms(row[1024 + w * HDq + lane], lane, t, cosp, sinp);
  Kb[((long)((b * 4 + w) * Tq + t)) * 64 + lane] = f2bf(kv);

#pragma unroll
  for (int hi = 0; hi < 4; hi++) {
    int h = hi * 4 + w;         // hkv = hi, g = w
    float q = rope_rms(row[h * HDq + lane], lane, t, cosp, sinp);
    Qb[((long)(((b * 4 + hi) * 4 + w) * Tq + t)) * 64 + lane] = f2bf(q);
  }
}

// ---------------------------------------------------------------------------
// MFMA flash attention, sliding window 1024 (unchanged math from round 2;
// output now bf16 Yb for the proj MFMA GEMM).
// ---------------------------------------------------------------------------
#define CEXP 0.18033688011112042f  // 0.125 * log2(e)

__global__ __launch_bounds__(256) void attn_mfma(
    const unsigned short* __restrict__ Qb, const unsigned short* __restrict__ Kb,
    const unsigned short* __restrict__ Vtb, unsigned short* __restrict__ Yb) {
  __shared__ __attribute__((aligned(16))) unsigned short Ks[64 * 64];
  __shared__ __attribute__((aligned(16))) unsigned short Vts[64 * 64];
  __shared__ float Ps[4 * 16 * 68];

  int bid = blockIdx.x;
  int qt = bid & 127;
  int hkv = (bid >> 7) & 3;
  int b = bid >> 9;
  int tid = threadIdx.x;
  int g = tid >> 6;
  int lane = tid & 63;
  int quad = lane >> 4;
  int l16 = lane & 15;

  const unsigned short* qb =
      Qb + ((long)(((b * 4 + hkv) * 4 + g) * Tq + qt * 16 + l16)) * 64 + quad * 8;
  short8 QA0 = *(const short8*)(qb);
  short8 QA1 = *(const short8*)(qb + 32);

  f32x4 O[4];
#pragma unroll
  for (int nt = 0; nt < 4; nt++) O[nt] = (f32x4){0.f, 0.f, 0.f, 0.f};
  float m[4] = {-1e30f, -1e30f, -1e30f, -1e30f};
  float l[4] = {0.f, 0.f, 0.f, 0.f};

  int lo = qt * 16 - (WSq - 1);
  int st = (lo < 0 ? 0 : lo) >> 6;
  int et = (qt * 16 + 15) >> 6;

  const unsigned short* Kbase = Kb + ((long)((b * 4 + hkv) * Tq)) * 64;
  const unsigned short* Vbase = Vtb + ((long)((b * 4 + hkv) * 64)) * Tq;
  float* myPs = Ps + g * 16 * 68;

  for (int kt = st; kt <= et; kt++) {
    int k0 = kt * 64;
    __syncthreads();
#pragma unroll
    for (int c = tid; c < 512; c += 256) {
      int row = c >> 3, gl = c & 7;
      *(uint4*)(&Ks[row * 64 + ((gl ^ (row & 7)) * 8)]) =
          *(const uint4*)(Kbase + ((long)(k0 + row)) * 64 + gl * 8);
      *(uint4*)(&Vts[row * 64 + ((gl ^ (row & 7)) * 8)]) =
          *(const uint4*)(Vbase + (long)row * Tq + k0 + gl * 8);
    }
    __syncthreads();

    f32x4 S4[4];
#pragma unroll
    for (int nt = 0; nt < 4; nt++) {
      int key = nt * 16 + l16;
      short8 kb0 = *(const short8*)(&Ks[key * 64 + ((quad ^ (key & 7)) * 8)]);
      short8 kb1 = *(const short8*)(&Ks[key * 64 + (((quad + 4) ^ (key & 7)) * 8)]);
      f32x4 acc = (f32x4){0.f, 0.f, 0.f, 0.f};
      acc = __builtin_amdgcn_mfma_f32_16x16x32_bf16(QA0, kb0, acc, 0, 0, 0);
      acc = __builtin_amdgcn_mfma_f32_16x16x32_bf16(QA1, kb1, acc, 0, 0, 0);
      S4[nt] = acc;
    }

    float Sv[4][4];
    float rm[4] = {-1e30f, -1e30f, -1e30f, -1e30f};
#pragma unroll
    for (int nt = 0; nt < 4; nt++) {
      int kpos = k0 + nt * 16 + l16;
#pragma unroll
      for (int r = 0; r < 4; r++) {
        int qpos = qt * 16 + quad * 4 + r;
        bool valid = (kpos <= qpos) && (kpos >= qpos - (WSq - 1));
        float s = valid ? S4[nt][r] : -1e30f;
        Sv[nt][r] = s;
        rm[r] = fmaxf(rm[r], s);
      }
    }
#pragma unroll
    for (int r = 0; r < 4; r++) {
      float v = rm[r];
      v = fmaxf(v, __shfl_xor(v, 1));
      v = fmaxf(v, __shfl_xor(v, 2));
      v = fmaxf(v, __shfl_xor(v, 4));
      v = fmaxf(v, __shfl_xor(v, 8));
      rm[r] = v;
    }
    float al[4], rs[4];
#pragma unroll
    for (int r = 0; r < 4; r++) {
      float mn = fmaxf(m[r], rm[r]);
      al[r] = exp2f((m[r] - mn) * CEXP);
      m[r] = mn;
      rs[r] = 0.f;
    }
    float Pv[4][4];
#pragma unroll
    for (int nt = 0; nt < 4; nt++) {
#pragma unroll
      for (int r = 0; r < 4; r++) {
        float s = Sv[nt][r];
        float p = (s > -5e29f) ? exp2f((s - m[r]) * CEXP) : 0.f;
        Pv[nt][r] = p;
        rs[r] += p;
      }
    }
#pragma unroll
    for (int r = 0; r < 4; r++) {
      float v = rs[r];
      v += __shfl_xor(v, 1);
      v += __shfl_xor(v, 2);
      v += __shfl_xor(v, 4);
      v += __shfl_xor(v, 8);
      l[r] = l[r] * al[r] + v;
    }
#pragma unroll
    for (int nt = 0; nt < 4; nt++)
#pragma unroll
      for (int r = 0; r < 4; r++) O[nt][r] *= al[r];

#pragma unroll
    for (int nt = 0; nt < 4; nt++)
#pragma unroll
      for (int r = 0; r < 4; r++)
        myPs[(quad * 4 + r) * 68 + nt * 16 + l16] = Pv[nt][r];

    const float* prow = myPs + l16 * 68;
    f32x4 a0 = *(const f32x4*)(prow + quad * 8);
    f32x4 a1 = *(const f32x4*)(prow + quad * 8 + 4);
    f32x4 b0 = *(const f32x4*)(prow + 32 + quad * 8);
    f32x4 b1 = *(const f32x4*)(prow + 32 + quad * 8 + 4);
    union { short8 s; unsigned short u[8]; } pa0, pa1;
#pragma unroll
    for (int j = 0; j < 4; j++) {
      pa0.u[j] = f2bf(a0[j]);
      pa0.u[4 + j] = f2bf(a1[j]);
      pa1.u[j] = f2bf(b0[j]);
      pa1.u[4 + j] = f2bf(b1[j]);
    }

#pragma unroll
    for (int nt = 0; nt < 4; nt++) {
      int d = nt * 16 + l16;
      short8 vb0 = *(const short8*)(&Vts[d * 64 + ((quad ^ (l16 & 7)) * 8)]);
      short8 vb1 = *(const short8*)(&Vts[d * 64 + (((quad + 4) ^ (l16 & 7)) * 8)]);
      O[nt] = __builtin_amdgcn_mfma_f32_16x16x32_bf16(pa0.s, vb0, O[nt], 0, 0, 0);
      O[nt] = __builtin_amdgcn_mfma_f32_16x16x32_bf16(pa1.s, vb1, O[nt], 0, 0, 0);
    }
  }

  float inv[4];
#pragma unroll
  for (int r = 0; r < 4; r++) inv[r] = 1.f / l[r];
  int h = hkv * 4 + g;
#pragma unroll
  for (int nt = 0; nt < 4; nt++)
#pragma unroll
    for (int r = 0; r < 4; r++)
      Yb[((long)(b * Tq + qt * 16 + quad * 4 + r)) * 1024 + h * 64 + nt * 16 +
         l16] = f2bf(O[nt][r] * inv[r]);
}

// ---------------------------------------------------------------------------
extern "C" void kernel_launch(void* const* d_in, const int* in_sizes, int n_in,
                              void* d_out, int out_size, void* d_ws,
                              size_t ws_size, hipStream_t stream) {
  const float* x     = (const float*)d_in[0];
  const float* ve    = (const float*)d_in[1];
  const float* cosp  = (const float*)d_in[2];
  const float* sinp  = (const float*)d_in[3];
  const float* Wq    = (const float*)d_in[4];
  const float* Wk    = (const float*)d_in[5];
  const float* Wv    = (const float*)d_in[6];
  const float* Wproj = (const float*)d_in[7];
  const float* Wg    = (const float*)d_in[8];

  // workspace layout (~39 MB), with aliasing over dead buffers:
  //  [0,              8,388,608)   xb bf16        -> Qb bf16 (after qkv gemm)
  //  [8,388,608,     11,534,336)   WqkvT bf16     -> Kb bf16 (after qkv gemm)
  //  [11,534,336,    13,631,488)   WprojT bf16    (persistent)
  //  [13,631,488,    38,797,312)   QKV f32        -> Yb bf16 (after postproc)
  //  [38,797,312,    40,894,464)   Vtb bf16
  char* base = (char*)d_ws;
  unsigned short* xb     = (unsigned short*)(base);
  unsigned short* Qb     = xb;
  unsigned short* WqkvT  = (unsigned short*)(base + 8388608);
  unsigned short* Kb     = WqkvT;
  unsigned short* WprojT = (unsigned short*)(base + 11534336);
  float*          QKV    = (float*)(base + 13631488);
  unsigned short* Yb     = (unsigned short*)(base + 13631488);
  unsigned short* Vtb    = (unsigned short*)(base + 38797312);
  float* out = (float*)d_out;

  cast_bf16<<<2048, 256, 0, stream>>>(x, xb);                       // x -> bf16
  wtrans<<<dim3(16, 16), 256, 0, stream>>>(Wq, WqkvT, 1024);
  wtrans<<<dim3(4, 16), 256, 0, stream>>>(Wk, WqkvT + 1024 * 1024, 256);
  wtrans<<<dim3(4, 16), 256, 0, stream>>>(Wv, WqkvT + 1280 * 1024, 256);
  wtrans<<<dim3(16, 16), 256, 0, stream>>>(Wproj, WprojT, 1024);

  gemm_bt<<<dim3(12, 32), 256, 0, stream>>>(xb, WqkvT, QKV, 4096, 1536, 1024);
  postproc<<<Bq * Tq, 256, 0, stream>>>(x, ve, cosp, sinp, Wg, QKV, Qb, Kb,
                                        Vtb);
  attn_mfma<<<Bq * HKVq * (Tq / 16), 256, 0, stream>>>(Qb, Kb, Vtb, Yb);
  gemm_bt<<<dim3(8, 32), 256, 0, stream>>>(Yb, WprojT, out, 4096, 1024, 1024);
}

// Round 4
// 190.481 us; speedup vs baseline: 5.6990x; 1.2792x over previous
//
#include <hip/hip_runtime.h>
#include <hip/hip_bf16.h>

// Problem constants
#define Bq 2
#define Tq 2048
#define Cq 1024
#define Hq 16
#define HKVq 4
#define HDq 64
#define Gq 4
#define WSq 1024
#define GATE_CHq 32

typedef __attribute__((ext_vector_type(8))) short short8;   // 8 bf16 (4 VGPRs)
typedef __attribute__((ext_vector_type(4))) float f32x4;    // MFMA C/D frag
typedef __attribute__((ext_vector_type(2))) unsigned int u32x2;
typedef unsigned int u32;
typedef unsigned short u16;

#if __has_builtin(__builtin_amdgcn_exp2f)
#define EXP2(x) __builtin_amdgcn_exp2f(x)
#else
#define EXP2(x) exp2f(x)
#endif

__device__ __forceinline__ u16 f2bf(float f) {
  u32 u = __float_as_uint(f);
  u32 r = (u + 0x7FFFu + ((u >> 16) & 1u)) >> 16;  // RNE
  return (u16)r;
}
__device__ __forceinline__ float bf2f(u16 u) {
  return __uint_as_float(((u32)u) << 16);
}

__device__ __forceinline__ void gl_lds16(const u16* g, u16* l) {
  __builtin_amdgcn_global_load_lds(
      (const u32 __attribute__((address_space(1)))*)g,
      (u32 __attribute__((address_space(3)))*)l, 16, 0, 0);
}

// ---------------------------------------------------------------------------
// bf16 MFMA GEMM: C[M][N] = A[M][K] @ Bt[N][K]^T. 64x128 tile, BK=32,
// 256 threads (4 waves, 32x64 each). global_load_lds staging with granule-XOR
// swizzle (phys = glog ^ ((m>>1)&3)); frag ds_read_b128 are 2-way (free).
// M%64==0, N%128==0, K%32==0. BF16OUT selects output type.
// ---------------------------------------------------------------------------
template <bool BF16OUT>
__global__ __launch_bounds__(256) void gemm_bt(
    const u16* __restrict__ A, const u16* __restrict__ Bt,
    void* __restrict__ Cv, int M, int N, int K) {
  __shared__ __attribute__((aligned(16))) u16 As[64 * 32];
  __shared__ __attribute__((aligned(16))) u16 Bs[128 * 32];

  const int bm0 = blockIdx.y * 64, bn0 = blockIdx.x * 128;
  const int tid = threadIdx.x;
  const int w = tid >> 6, lane = tid & 63;
  const int wm = (w >> 1) * 32, wn = (w & 1) * 64;
  const int quad = lane >> 4, l16 = lane & 15;

  f32x4 acc[2][4];
#pragma unroll
  for (int mt = 0; mt < 2; mt++)
#pragma unroll
    for (int nt = 0; nt < 4; nt++) acc[mt][nt] = (f32x4){0.f, 0.f, 0.f, 0.f};

  // staging offsets: slot s -> row m = s>>2, granule gp = s&3, swizzled
  const int mA = tid >> 2, gpA = tid & 3;
  const int goffA = mA * K + (gpA ^ ((mA >> 1) & 3)) * 8;
  int goffB[2];
#pragma unroll
  for (int i = 0; i < 2; i++) {
    int s = i * 256 + tid;
    int m = s >> 2, gp = s & 3;
    goffB[i] = m * K + (gp ^ ((m >> 1) & 3)) * 8;
  }
  const u16* Ab = A + (long)bm0 * K;
  const u16* Bb = Bt + (long)bn0 * K;

  const u16* pA[2];
  const u16* pB[4];
#pragma unroll
  for (int t = 0; t < 2; t++) {
    int ml = wm + t * 16 + l16;
    pA[t] = &As[(ml * 4 + (quad ^ ((ml >> 1) & 3))) * 8];
  }
#pragma unroll
  for (int t = 0; t < 4; t++) {
    int nl = wn + t * 16 + l16;
    pB[t] = &Bs[(nl * 4 + (quad ^ ((nl >> 1) & 3))) * 8];
  }

  for (int k0 = 0; k0 < K; k0 += 32) {
    __syncthreads();
    gl_lds16(Ab + goffA + k0, &As[(w * 64) * 8]);
#pragma unroll
    for (int i = 0; i < 2; i++)
      gl_lds16(Bb + goffB[i] + k0, &Bs[(i * 256 + w * 64) * 8]);
    __syncthreads();

    short8 af[2], bf[4];
#pragma unroll
    for (int t = 0; t < 2; t++) af[t] = *(const short8*)pA[t];
#pragma unroll
    for (int t = 0; t < 4; t++) bf[t] = *(const short8*)pB[t];
#pragma unroll
    for (int mt = 0; mt < 2; mt++)
#pragma unroll
      for (int nt = 0; nt < 4; nt++)
        acc[mt][nt] = __builtin_amdgcn_mfma_f32_16x16x32_bf16(
            af[mt], bf[nt], acc[mt][nt], 0, 0, 0);
  }

#pragma unroll
  for (int mt = 0; mt < 2; mt++)
#pragma unroll
    for (int nt = 0; nt < 4; nt++) {
      int row0 = bm0 + wm + mt * 16 + quad * 4;
      int col = bn0 + wn + nt * 16 + l16;
#pragma unroll
      for (int r = 0; r < 4; r++) {
        if (BF16OUT)
          ((u16*)Cv)[(long)(row0 + r) * N + col] = f2bf(acc[mt][nt][r]);
        else
          ((float*)Cv)[(long)(row0 + r) * N + col] = acc[mt][nt][r];
      }
    }
}

// ---------------------------------------------------------------------------
// f32 -> bf16 flat cast
// ---------------------------------------------------------------------------
__global__ __launch_bounds__(256) void cast_bf16(const float* __restrict__ S,
                                                 u16* __restrict__ D) {
  int i = (blockIdx.x * 256 + threadIdx.x) * 8;
  float4 a = *(const float4*)(S + i);
  float4 b = *(const float4*)(S + i + 4);
  union { short8 v; u16 u[8]; } o;
  o.u[0] = f2bf(a.x); o.u[1] = f2bf(a.y); o.u[2] = f2bf(a.z); o.u[3] = f2bf(a.w);
  o.u[4] = f2bf(b.x); o.u[5] = f2bf(b.y); o.u[6] = f2bf(b.z); o.u[7] = f2bf(b.w);
  *(short8*)(D + i) = o.v;
}

// ---------------------------------------------------------------------------
// Weight transpose + cast: S[1024][N] f32 -> D[N][1024] bf16
// ---------------------------------------------------------------------------
__device__ __forceinline__ void wtrans_body(const float* __restrict__ S,
                                            u16* __restrict__ D, int N, int n0,
                                            int k0, float (*tile)[65]) {
  int tid = threadIdx.x;
#pragma unroll
  for (int i = 0; i < 16; i++) {
    int idx = i * 256 + tid;
    int kl = idx >> 6, nl = idx & 63;
    tile[kl][nl] = S[(long)(k0 + kl) * N + n0 + nl];
  }
  __syncthreads();
#pragma unroll
  for (int i = 0; i < 16; i++) {
    int idx = i * 256 + tid;
    int nl = idx >> 6, kl = idx & 63;
    D[(long)(n0 + nl) * 1024 + k0 + kl] = f2bf(tile[kl][nl]);
  }
}

__global__ __launch_bounds__(256) void wtrans(const float* __restrict__ S,
                                              u16* __restrict__ D, int N) {
  __shared__ float tile[64][65];
  wtrans_body(S, D, N, blockIdx.x * 64, blockIdx.y * 64, tile);
}

__global__ __launch_bounds__(256) void wtrans_qkv(
    const float* __restrict__ Wq, const float* __restrict__ Wk,
    const float* __restrict__ Wv, u16* __restrict__ D) {
  __shared__ float tile[64][65];
  int bx = blockIdx.x;
  const float* S;
  u16* Dst;
  int N, nb;
  if (bx < 16)      { S = Wq; N = 1024; nb = bx;      Dst = D; }
  else if (bx < 20) { S = Wk; N = 256;  nb = bx - 16; Dst = D + 1024 * 1024; }
  else              { S = Wv; N = 256;  nb = bx - 20; Dst = D + 1280 * 1024; }
  wtrans_body(S, Dst, N, nb * 64, blockIdx.y * 64, tile);
}

// ---------------------------------------------------------------------------
// Postprocess: gate+ve into V (row-major Vb); RoPE+RMSNorm on Q,K; bf16 out.
//   Qb[b][hkv][g][t][d], Kb[b][hkv][t][d], Vb[b][hkv][t][d]
// ---------------------------------------------------------------------------
__device__ __forceinline__ float rope_rms(float u, int lane, float c, float s) {
  float up = __shfl_xor(u, 32);
  float r = (lane < 32) ? (u * c + up * s) : (u * c - up * s);
  float sum = r * r;
#pragma unroll
  for (int off = 32; off >= 1; off >>= 1) sum += __shfl_xor(sum, off);
  return r * rsqrtf(sum * (1.f / 64.f) + 1.1920928955078125e-07f);
}

__global__ __launch_bounds__(256) void postproc(
    const float* __restrict__ x, const float* __restrict__ ve,
    const float* __restrict__ cosp, const float* __restrict__ sinp,
    const float* __restrict__ Wg, const u16* __restrict__ QKV,
    u16* __restrict__ Qb, u16* __restrict__ Kb, u16* __restrict__ Vb) {
  int bt = blockIdx.x;          // b*T + t
  int b = bt >> 11;
  int t = bt & (Tq - 1);
  int tid = threadIdx.x;
  int w = tid >> 6;             // kv head
  int lane = tid & 63;
  const u16* row = QKV + (long)bt * 1536;

  float c = cosp[t * 32 + (lane & 31)];
  float s = sinp[t * 32 + (lane & 31)];

  float pg = 0.f;
  if (lane < 32) pg = x[(long)bt * Cq + lane] * Wg[lane * HKVq + w];
#pragma unroll
  for (int off = 16; off >= 1; off >>= 1) pg += __shfl_xor(pg, off);
  float z = __shfl(pg, 0);
  float gate = 2.f / (1.f + expf(-z));

  long vi = (long)bt * (HKVq * HDq) + w * HDq + lane;
  float v = bf2f(row[1280 + w * HDq + lane]) + gate * ve[vi];
  Vb[((long)((b * 4 + w) * Tq + t)) * 64 + lane] = f2bf(v);

  float kv = rope_rms(bf2f(row[1024 + w * HDq + lane]), lane, c, s);
  Kb[((long)((b * 4 + w) * Tq + t)) * 64 + lane] = f2bf(kv);

#pragma unroll
  for (int hi = 0; hi < 4; hi++) {
    int h = hi * 4 + w;         // hkv = hi, g = w
    float q = rope_rms(bf2f(row[h * HDq + lane]), lane, c, s);
    Qb[((long)(((b * 4 + hi) * 4 + w) * Tq + t)) * 64 + lane] = f2bf(q);
  }
}

// ---------------------------------------------------------------------------
// V transpose: Vb[bh][t][d] -> Vtb[bh][d][t], coalesced both sides.
// ---------------------------------------------------------------------------
__global__ __launch_bounds__(256) void vtrans(const u16* __restrict__ Vb,
                                              u16* __restrict__ Vtb) {
  __shared__ u16 tile[64][74];  // stride 74 shorts (37 dwords) -> 2-way banks
  int bh = blockIdx.y;
  int t0 = blockIdx.x * 64;
  int tid = threadIdx.x;
  const u16* src = Vb + ((long)bh * Tq + t0) * 64;
  u16* dst = Vtb + (long)bh * 64 * Tq + t0;
#pragma unroll
  for (int i = 0; i < 16; i++) {
    int idx = i * 256 + tid;
    int r = idx >> 6, cl = idx & 63;
    tile[r][cl] = src[(long)r * 64 + cl];
  }
  __syncthreads();
#pragma unroll
  for (int i = 0; i < 16; i++) {
    int idx = i * 256 + tid;
    int d = idx >> 6, t = idx & 63;
    dst[(long)d * Tq + t] = tile[t][d];
  }
}

// ---------------------------------------------------------------------------
// MFMA flash attention v2, sliding window 1024, fixed-max softmax.
// Block = (b, hkv, 16-q tile); 4 waves = 4 GQA heads.
// Computes S^T = K·Q^T (so q = l16 per lane): per-lane scalar l-partials,
// no running max / no O rescale (s <= 8 guaranteed by RMS norm).
// ---------------------------------------------------------------------------
#define CEXP 0.18033688011112042f   // 0.125 * log2(e)
#define CEXP8 1.4426950408889634f   // 8 * 0.125 * log2(e)

__device__ __forceinline__ void attn_tile(
    int k0, bool maskC, bool maskW, int qpos, int quad, int l16,
    const u16* __restrict__ Ks, const u16* __restrict__ Vts,
    u32* __restrict__ myPs, short8 QB0, short8 QB1, f32x4* O, float& lsum) {
  // S^T = K·Q^T : A = K-frag (m=key), B = Q-frag (n=q)
  f32x4 S4[4];
#pragma unroll
  for (int nt = 0; nt < 4; nt++) {
    int key = nt * 16 + l16;
    short8 kb0 = *(const short8*)(&Ks[key * 64 + ((quad ^ (key & 7)) * 8)]);
    short8 kb1 = *(const short8*)(&Ks[key * 64 + (((quad + 4) ^ (key & 7)) * 8)]);
    f32x4 acc = (f32x4){0.f, 0.f, 0.f, 0.f};
    acc = __builtin_amdgcn_mfma_f32_16x16x32_bf16(kb0, QB0, acc, 0, 0, 0);
    acc = __builtin_amdgcn_mfma_f32_16x16x32_bf16(kb1, QB1, acc, 0, 0, 0);
    S4[nt] = acc;
  }

  // p = exp2(s*CEXP - CEXP8); rows = keys (quad*4+r), cols = q (l16)
  float Pv[4][4];
#pragma unroll
  for (int nt = 0; nt < 4; nt++) {
#pragma unroll
    for (int r = 0; r < 4; r++) {
      float sv = S4[nt][r];
      if (maskC || maskW) {
        int kpos = k0 + nt * 16 + quad * 4 + r;
        bool valid = true;
        if (maskC) valid = valid && (kpos <= qpos);
        if (maskW) valid = valid && (kpos >= qpos - (WSq - 1));
        sv = valid ? sv : -1e30f;
      }
      float p = EXP2(__builtin_fmaf(sv, CEXP, -CEXP8));
      Pv[nt][r] = p;
      lsum += p;
    }
  }

  // pack bf16 pairs (round-nearest via +0x8000) -> per-wave LDS, then read
  // P A-frags (m=q=l16, k=key contiguous).
#pragma unroll
  for (int nt = 0; nt < 4; nt++) {
    u32x2 pk;
#pragma unroll
    for (int rp = 0; rp < 2; rp++) {
      u32 lo = __float_as_uint(Pv[nt][2 * rp]) + 0x8000u;
      u32 hi = __float_as_uint(Pv[nt][2 * rp + 1]) + 0x8000u;
      pk[rp] = __builtin_amdgcn_perm(hi, lo, 0x07060302u);
    }
    *(u32x2*)(&myPs[l16 * 36 + 8 * nt + 2 * quad]) = pk;
  }
  short8 pa0 = *(const short8*)(&myPs[l16 * 36 + quad * 4]);
  short8 pa1 = *(const short8*)(&myPs[l16 * 36 + 16 + quad * 4]);

  // O += P·V : B = V^T-frag (n=d, k=key)
#pragma unroll
  for (int nt = 0; nt < 4; nt++) {
    int d = nt * 16 + l16;
    short8 vb0 = *(const short8*)(&Vts[d * 64 + ((quad ^ (d & 7)) * 8)]);
    short8 vb1 = *(const short8*)(&Vts[d * 64 + (((quad + 4) ^ (d & 7)) * 8)]);
    O[nt] = __builtin_amdgcn_mfma_f32_16x16x32_bf16(pa0, vb0, O[nt], 0, 0, 0);
    O[nt] = __builtin_amdgcn_mfma_f32_16x16x32_bf16(pa1, vb1, O[nt], 0, 0, 0);
  }
}

__global__ __launch_bounds__(256) void attn_mfma(
    const u16* __restrict__ Qb, const u16* __restrict__ Kb,
    const u16* __restrict__ Vtb, u16* __restrict__ Yb) {
  __shared__ __attribute__((aligned(16))) u16 Ks[64 * 64];
  __shared__ __attribute__((aligned(16))) u16 Vts[64 * 64];
  __shared__ __attribute__((aligned(16))) u32 Ps[4][16 * 36];

  int bid = blockIdx.x;
  int qt = bid & 127;
  int hkv = (bid >> 7) & 3;
  int b = bid >> 9;
  int tid = threadIdx.x;
  int g = tid >> 6;
  int lane = tid & 63;
  int quad = lane >> 4;
  int l16 = lane & 15;
  int qpos = qt * 16 + l16;

  // Q B-frag (n = l16 = q, k = quad*8+j)
  const u16* qb =
      Qb + ((long)(((b * 4 + hkv) * 4 + g) * Tq + qt * 16 + l16)) * 64 + quad * 8;
  short8 QB0 = *(const short8*)(qb);
  short8 QB1 = *(const short8*)(qb + 32);

  f32x4 O[4];
#pragma unroll
  for (int nt = 0; nt < 4; nt++) O[nt] = (f32x4){0.f, 0.f, 0.f, 0.f};
  float lsum = 0.f;

  int lo = qt * 16 - (WSq - 1);
  int st = (lo < 0 ? 0 : lo) >> 6;
  int et = (qt * 16 + 15) >> 6;
  bool needW = (qt >= 64);

  const u16* Kbase = Kb + ((long)((b * 4 + hkv) * Tq)) * 64;
  const u16* Vbase = Vtb + ((long)((b * 4 + hkv) * 64)) * Tq;
  u32* myPs = &Ps[g][0];

  // staging: slot s = i*256+tid; K: row=s>>3, gran=s&7 (XOR swizzled source)
  int rowoffK[2], rowoffV[2];
#pragma unroll
  for (int i = 0; i < 2; i++) {
    int s = i * 256 + tid;
    int row = s >> 3, gl = s & 7;
    rowoffK[i] = row * 64 + (gl ^ (row & 7)) * 8;
    rowoffV[i] = row * Tq + (gl ^ (row & 7)) * 8;
  }

  for (int kt = st; kt <= et; kt++) {
    int k0 = kt * 64;
    __syncthreads();
#pragma unroll
    for (int i = 0; i < 2; i++) {
      gl_lds16(Kbase + (long)k0 * 64 + rowoffK[i], &Ks[(i * 256 + g * 64) * 8]);
      gl_lds16(Vbase + k0 + rowoffV[i], &Vts[(i * 256 + g * 64) * 8]);
    }
    __syncthreads();

    if (kt == et)
      attn_tile(k0, true, needW && (kt == st), qpos, quad, l16, Ks, Vts, myPs,
                QB0, QB1, O, lsum);
    else if (kt == st && needW)
      attn_tile(k0, false, true, qpos, quad, l16, Ks, Vts, myPs, QB0, QB1, O,
                lsum);
    else
      attn_tile(k0, false, false, qpos, quad, l16, Ks, Vts, myPs, QB0, QB1, O,
                lsum);
  }

  // reduce l across quads (keys were partitioned over quads/regs)
  lsum += __shfl_xor(lsum, 16);
  lsum += __shfl_xor(lsum, 32);
  // lane (quad,l16) needs 1/l for rows q = quad*4+r
  float invl[4];
#pragma unroll
  for (int r = 0; r < 4; r++) invl[r] = 1.f / __shfl(lsum, quad * 4 + r);

  int h = hkv * 4 + g;
#pragma unroll
  for (int nt = 0; nt < 4; nt++)
#pragma unroll
    for (int r = 0; r < 4; r++)
      Yb[((long)(b * Tq + qt * 16 + quad * 4 + r)) * 1024 + h * 64 + nt * 16 +
         l16] = f2bf(O[nt][r] * invl[r]);
}

// ---------------------------------------------------------------------------
extern "C" void kernel_launch(void* const* d_in, const int* in_sizes, int n_in,
                              void* d_out, int out_size, void* d_ws,
                              size_t ws_size, hipStream_t stream) {
  const float* x     = (const float*)d_in[0];
  const float* ve    = (const float*)d_in[1];
  const float* cosp  = (const float*)d_in[2];
  const float* sinp  = (const float*)d_in[3];
  const float* Wq    = (const float*)d_in[4];
  const float* Wk    = (const float*)d_in[5];
  const float* Wv    = (const float*)d_in[6];
  const float* Wproj = (const float*)d_in[7];
  const float* Wg    = (const float*)d_in[8];

  // workspace layout (38.8 MB), aliasing dead buffers:
  //  [ 0        ,  8,388,608)  xb bf16        -> Qb bf16 (after qkv gemm)
  //  [ 8,388,608, 11,534,336)  WqkvT bf16     -> Kb bf16 (after qkv gemm)
  //  [11,534,336, 13,631,488)  WprojT bf16    (persistent)
  //  [13,631,488, 26,214,400)  QKVb bf16 [4096][1536]
  //  [26,214,400, 28,311,552)  Vb bf16
  //  [28,311,552, 30,408,704)  Vtb bf16
  //  [30,408,704, 38,797,312)  Yb bf16
  char* base = (char*)d_ws;
  u16* xb     = (u16*)(base);
  u16* Qb     = xb;
  u16* WqkvT  = (u16*)(base + 8388608);
  u16* Kb     = WqkvT;
  u16* WprojT = (u16*)(base + 11534336);
  u16* QKVb   = (u16*)(base + 13631488);
  u16* Vb     = (u16*)(base + 26214400);
  u16* Vtb    = (u16*)(base + 28311552);
  u16* Yb     = (u16*)(base + 30408704);
  float* out = (float*)d_out;

  cast_bf16<<<2048, 256, 0, stream>>>(x, xb);
  wtrans_qkv<<<dim3(24, 16), 256, 0, stream>>>(Wq, Wk, Wv, WqkvT);
  wtrans<<<dim3(16, 16), 256, 0, stream>>>(Wproj, WprojT, 1024);

  gemm_bt<true><<<dim3(12, 64), 256, 0, stream>>>(xb, WqkvT, QKVb, 4096, 1536,
                                                  1024);
  postproc<<<Bq * Tq, 256, 0, stream>>>(x, ve, cosp, sinp, Wg, QKVb, Qb, Kb,
                                        Vb);
  vtrans<<<dim3(32, 8), 256, 0, stream>>>(Vb, Vtb);
  attn_mfma<<<Bq * HKVq * (Tq / 16), 256, 0, stream>>>(Qb, Kb, Vtb, Yb);
  gemm_bt<false><<<dim3(8, 64), 256, 0, stream>>>(Yb, WprojT, out, 4096, 1024,
                                                  1024);
}

// Round 5
// 186.240 us; speedup vs baseline: 5.8288x; 1.0228x over previous
//
#include <hip/hip_runtime.h>
#include <hip/hip_bf16.h>

// Problem constants
#define Bq 2
#define Tq 2048
#define Cq 1024
#define Hq 16
#define HKVq 4
#define HDq 64
#define Gq 4
#define WSq 1024
#define GATE_CHq 32

typedef __attribute__((ext_vector_type(8))) short short8;   // 8 bf16 (4 VGPRs)
typedef __attribute__((ext_vector_type(4))) float f32x4;    // MFMA C/D frag
typedef __attribute__((ext_vector_type(2))) unsigned int u32x2;
typedef unsigned int u32;
typedef unsigned short u16;

#if __has_builtin(__builtin_amdgcn_exp2f)
#define EXP2(x) __builtin_amdgcn_exp2f(x)
#else
#define EXP2(x) exp2f(x)
#endif

__device__ __forceinline__ u16 f2bf(float f) {
  u32 u = __float_as_uint(f);
  u32 r = (u + 0x7FFFu + ((u >> 16) & 1u)) >> 16;  // RNE
  return (u16)r;
}
__device__ __forceinline__ float bf2f(u16 u) {
  return __uint_as_float(((u32)u) << 16);
}

__device__ __forceinline__ void gl_lds16(const u16* g, u16* l) {
  __builtin_amdgcn_global_load_lds(
      (const u32 __attribute__((address_space(1)))*)g,
      (u32 __attribute__((address_space(3)))*)l, 16, 0, 0);
}

// ---------------------------------------------------------------------------
// bf16 MFMA GEMM: C[M][N] = A[M][K] @ Bt[N][K]^T. 64x128 tile, BK=32,
// 256 threads (4 waves, 32x64 each). global_load_lds staging with granule-XOR
// swizzle; frag ds_read_b128 are 2-way (free).
// ---------------------------------------------------------------------------
template <bool BF16OUT>
__global__ __launch_bounds__(256) void gemm_bt(
    const u16* __restrict__ A, const u16* __restrict__ Bt,
    void* __restrict__ Cv, int M, int N, int K) {
  __shared__ __attribute__((aligned(16))) u16 As[64 * 32];
  __shared__ __attribute__((aligned(16))) u16 Bs[128 * 32];

  const int bm0 = blockIdx.y * 64, bn0 = blockIdx.x * 128;
  const int tid = threadIdx.x;
  const int w = tid >> 6, lane = tid & 63;
  const int wm = (w >> 1) * 32, wn = (w & 1) * 64;
  const int quad = lane >> 4, l16 = lane & 15;

  f32x4 acc[2][4];
#pragma unroll
  for (int mt = 0; mt < 2; mt++)
#pragma unroll
    for (int nt = 0; nt < 4; nt++) acc[mt][nt] = (f32x4){0.f, 0.f, 0.f, 0.f};

  const int mA = tid >> 2, gpA = tid & 3;
  const int goffA = mA * K + (gpA ^ ((mA >> 1) & 3)) * 8;
  int goffB[2];
#pragma unroll
  for (int i = 0; i < 2; i++) {
    int s = i * 256 + tid;
    int m = s >> 2, gp = s & 3;
    goffB[i] = m * K + (gp ^ ((m >> 1) & 3)) * 8;
  }
  const u16* Ab = A + (long)bm0 * K;
  const u16* Bb = Bt + (long)bn0 * K;

  const u16* pA[2];
  const u16* pB[4];
#pragma unroll
  for (int t = 0; t < 2; t++) {
    int ml = wm + t * 16 + l16;
    pA[t] = &As[(ml * 4 + (quad ^ ((ml >> 1) & 3))) * 8];
  }
#pragma unroll
  for (int t = 0; t < 4; t++) {
    int nl = wn + t * 16 + l16;
    pB[t] = &Bs[(nl * 4 + (quad ^ ((nl >> 1) & 3))) * 8];
  }

  for (int k0 = 0; k0 < K; k0 += 32) {
    __syncthreads();
    gl_lds16(Ab + goffA + k0, &As[(w * 64) * 8]);
#pragma unroll
    for (int i = 0; i < 2; i++)
      gl_lds16(Bb + goffB[i] + k0, &Bs[(i * 256 + w * 64) * 8]);
    __syncthreads();

    short8 af[2], bf[4];
#pragma unroll
    for (int t = 0; t < 2; t++) af[t] = *(const short8*)pA[t];
#pragma unroll
    for (int t = 0; t < 4; t++) bf[t] = *(const short8*)pB[t];
#pragma unroll
    for (int mt = 0; mt < 2; mt++)
#pragma unroll
      for (int nt = 0; nt < 4; nt++)
        acc[mt][nt] = __builtin_amdgcn_mfma_f32_16x16x32_bf16(
            af[mt], bf[nt], acc[mt][nt], 0, 0, 0);
  }

#pragma unroll
  for (int mt = 0; mt < 2; mt++)
#pragma unroll
    for (int nt = 0; nt < 4; nt++) {
      int row0 = bm0 + wm + mt * 16 + quad * 4;
      int col = bn0 + wn + nt * 16 + l16;
#pragma unroll
      for (int r = 0; r < 4; r++) {
        if (BF16OUT)
          ((u16*)Cv)[(long)(row0 + r) * N + col] = f2bf(acc[mt][nt][r]);
        else
          ((float*)Cv)[(long)(row0 + r) * N + col] = acc[mt][nt][r];
      }
    }
}

// ---------------------------------------------------------------------------
// f32 -> bf16 flat cast
// ---------------------------------------------------------------------------
__global__ __launch_bounds__(256) void cast_bf16(const float* __restrict__ S,
                                                 u16* __restrict__ D) {
  int i = (blockIdx.x * 256 + threadIdx.x) * 8;
  float4 a = *(const float4*)(S + i);
  float4 b = *(const float4*)(S + i + 4);
  union { short8 v; u16 u[8]; } o;
  o.u[0] = f2bf(a.x); o.u[1] = f2bf(a.y); o.u[2] = f2bf(a.z); o.u[3] = f2bf(a.w);
  o.u[4] = f2bf(b.x); o.u[5] = f2bf(b.y); o.u[6] = f2bf(b.z); o.u[7] = f2bf(b.w);
  *(short8*)(D + i) = o.v;
}

// ---------------------------------------------------------------------------
// All weight transposes in one launch: Wq/Wk/Wv -> WqkvT, Wproj -> WprojT
// ---------------------------------------------------------------------------
__device__ __forceinline__ void wtrans_body(const float* __restrict__ S,
                                            u16* __restrict__ D, int N, int n0,
                                            int k0, float (*tile)[65]) {
  int tid = threadIdx.x;
#pragma unroll
  for (int i = 0; i < 16; i++) {
    int idx = i * 256 + tid;
    int kl = idx >> 6, nl = idx & 63;
    tile[kl][nl] = S[(long)(k0 + kl) * N + n0 + nl];
  }
  __syncthreads();
#pragma unroll
  for (int i = 0; i < 16; i++) {
    int idx = i * 256 + tid;
    int nl = idx >> 6, kl = idx & 63;
    D[(long)(n0 + nl) * 1024 + k0 + kl] = f2bf(tile[kl][nl]);
  }
}

__global__ __launch_bounds__(256) void wtrans_all(
    const float* __restrict__ Wq, const float* __restrict__ Wk,
    const float* __restrict__ Wv, const float* __restrict__ Wproj,
    u16* __restrict__ Dqkv, u16* __restrict__ Dproj) {
  __shared__ float tile[64][65];
  int bx = blockIdx.x;
  const float* S;
  u16* Dst;
  int N, nb;
  if (bx < 16)      { S = Wq;    N = 1024; nb = bx;      Dst = Dqkv; }
  else if (bx < 20) { S = Wk;    N = 256;  nb = bx - 16; Dst = Dqkv + 1024 * 1024; }
  else if (bx < 24) { S = Wv;    N = 256;  nb = bx - 20; Dst = Dqkv + 1280 * 1024; }
  else              { S = Wproj; N = 1024; nb = bx - 24; Dst = Dproj; }
  wtrans_body(S, Dst, N, nb * 64, blockIdx.y * 64, tile);
}

// ---------------------------------------------------------------------------
// Postprocess: gate+ve into V (row-major Vb); RoPE+RMSNorm on Q,K; bf16 out.
// ---------------------------------------------------------------------------
__device__ __forceinline__ float rope_rms(float u, int lane, float c, float s) {
  float up = __shfl_xor(u, 32);
  float r = (lane < 32) ? (u * c + up * s) : (u * c - up * s);
  float sum = r * r;
#pragma unroll
  for (int off = 32; off >= 1; off >>= 1) sum += __shfl_xor(sum, off);
  return r * rsqrtf(sum * (1.f / 64.f) + 1.1920928955078125e-07f);
}

__global__ __launch_bounds__(256) void postproc(
    const float* __restrict__ x, const float* __restrict__ ve,
    const float* __restrict__ cosp, const float* __restrict__ sinp,
    const float* __restrict__ Wg, const u16* __restrict__ QKV,
    u16* __restrict__ Qb, u16* __restrict__ Kb, u16* __restrict__ Vb) {
  int bt = blockIdx.x;          // b*T + t
  int b = bt >> 11;
  int t = bt & (Tq - 1);
  int tid = threadIdx.x;
  int w = tid >> 6;             // kv head
  int lane = tid & 63;
  const u16* row = QKV + (long)bt * 1536;

  float c = cosp[t * 32 + (lane & 31)];
  float s = sinp[t * 32 + (lane & 31)];

  float pg = 0.f;
  if (lane < 32) pg = x[(long)bt * Cq + lane] * Wg[lane * HKVq + w];
#pragma unroll
  for (int off = 16; off >= 1; off >>= 1) pg += __shfl_xor(pg, off);
  float z = __shfl(pg, 0);
  float gate = 2.f / (1.f + expf(-z));

  long vi = (long)bt * (HKVq * HDq) + w * HDq + lane;
  float v = bf2f(row[1280 + w * HDq + lane]) + gate * ve[vi];
  Vb[((long)((b * 4 + w) * Tq + t)) * 64 + lane] = f2bf(v);

  float kv = rope_rms(bf2f(row[1024 + w * HDq + lane]), lane, c, s);
  Kb[((long)((b * 4 + w) * Tq + t)) * 64 + lane] = f2bf(kv);

#pragma unroll
  for (int hi = 0; hi < 4; hi++) {
    int h = hi * 4 + w;         // hkv = hi, g = w
    float q = rope_rms(bf2f(row[h * HDq + lane]), lane, c, s);
    Qb[((long)(((b * 4 + hi) * 4 + w) * Tq + t)) * 64 + lane] = f2bf(q);
  }
}

// ---------------------------------------------------------------------------
// V transpose: Vb[bh][t][d] -> Vtb[bh][d][t]
// ---------------------------------------------------------------------------
__global__ __launch_bounds__(256) void vtrans(const u16* __restrict__ Vb,
                                              u16* __restrict__ Vtb) {
  __shared__ u16 tile[64][74];
  int bh = blockIdx.y;
  int t0 = blockIdx.x * 64;
  int tid = threadIdx.x;
  const u16* src = Vb + ((long)bh * Tq + t0) * 64;
  u16* dst = Vtb + (long)bh * 64 * Tq + t0;
#pragma unroll
  for (int i = 0; i < 16; i++) {
    int idx = i * 256 + tid;
    int r = idx >> 6, cl = idx & 63;
    tile[r][cl] = src[(long)r * 64 + cl];
  }
  __syncthreads();
#pragma unroll
  for (int i = 0; i < 16; i++) {
    int idx = i * 256 + tid;
    int d = idx >> 6, t = idx & 63;
    dst[(long)d * Tq + t] = tile[t][d];
  }
}

// ---------------------------------------------------------------------------
// MFMA flash attention v3: q-tile = 32 per block, fixed-max softmax.
// Block = (b, hkv, qt32); 4 waves = 4 GQA heads. S^T = K·Q^T per q-subtile.
// 32 MFMA per wave per 64-key tile. bid&7 = (b*4+hkv) for XCD L2 locality.
// ---------------------------------------------------------------------------
#define CEXP 0.18033688011112042f   // 0.125 * log2(e)
#define CEXP8 1.4426950408889634f   // 8 * 0.125 * log2(e)

template <bool MASK>
__device__ __forceinline__ void attn_tile32(
    int k0, int q0, int quad, int l16, const u16* __restrict__ Ks,
    const u16* __restrict__ Vts, u32* __restrict__ myPs,
    const short8 (&QB)[2][2], f32x4 (&O)[2][4], float (&lsum)[2]) {
  // S^T = K·Q^T : A = K-frag (m=key), B = Q-frag (n=q)
  f32x4 S4[4][2];
#pragma unroll
  for (int kt4 = 0; kt4 < 4; kt4++) {
    int key = kt4 * 16 + l16;
    short8 kb0 = *(const short8*)(&Ks[key * 64 + ((quad ^ (key & 7)) * 8)]);
    short8 kb1 = *(const short8*)(&Ks[key * 64 + (((quad + 4) ^ (key & 7)) * 8)]);
#pragma unroll
    for (int qj = 0; qj < 2; qj++) {
      f32x4 acc = (f32x4){0.f, 0.f, 0.f, 0.f};
      acc = __builtin_amdgcn_mfma_f32_16x16x32_bf16(kb0, QB[qj][0], acc, 0, 0, 0);
      acc = __builtin_amdgcn_mfma_f32_16x16x32_bf16(kb1, QB[qj][1], acc, 0, 0, 0);
      S4[kt4][qj] = acc;
    }
  }

  // p = exp2(s*CEXP - CEXP8); pack bf16 pairs -> per-wave LDS
#pragma unroll
  for (int kt4 = 0; kt4 < 4; kt4++)
#pragma unroll
    for (int qj = 0; qj < 2; qj++) {
      float Pv[4];
#pragma unroll
      for (int r = 0; r < 4; r++) {
        float sv = S4[kt4][qj][r];
        if (MASK) {
          int kpos = k0 + kt4 * 16 + quad * 4 + r;
          int qpos = q0 + qj * 16 + l16;
          bool valid = (kpos <= qpos) && (kpos >= qpos - (WSq - 1));
          sv = valid ? sv : -1e30f;
        }
        float p = EXP2(__builtin_fmaf(sv, CEXP, -CEXP8));
        Pv[r] = p;
        lsum[qj] += p;
      }
      u32x2 pk;
#pragma unroll
      for (int rp = 0; rp < 2; rp++) {
        u32 lo = __float_as_uint(Pv[2 * rp]) + 0x8000u;
        u32 hi = __float_as_uint(Pv[2 * rp + 1]) + 0x8000u;
        pk[rp] = __builtin_amdgcn_perm(hi, lo, 0x07060302u);
      }
      *(u32x2*)(&myPs[(qj * 16 + l16) * 36 + kt4 * 8 + quad * 2]) = pk;
    }

  // V B-frags (shared across qj)
  short8 vb[4][2];
#pragma unroll
  for (int nt = 0; nt < 4; nt++) {
    int d = nt * 16 + l16;
    vb[nt][0] = *(const short8*)(&Vts[d * 64 + ((quad ^ (d & 7)) * 8)]);
    vb[nt][1] = *(const short8*)(&Vts[d * 64 + (((quad + 4) ^ (d & 7)) * 8)]);
  }

  // O += P·V : A = P (m=q, k=key)
#pragma unroll
  for (int qj = 0; qj < 2; qj++) {
    const u32* prow = &myPs[(qj * 16 + l16) * 36];
    short8 pa0 = *(const short8*)(prow + quad * 4);
    short8 pa1 = *(const short8*)(prow + 16 + quad * 4);
#pragma unroll
    for (int nt = 0; nt < 4; nt++) {
      O[qj][nt] =
          __builtin_amdgcn_mfma_f32_16x16x32_bf16(pa0, vb[nt][0], O[qj][nt], 0, 0, 0);
      O[qj][nt] =
          __builtin_amdgcn_mfma_f32_16x16x32_bf16(pa1, vb[nt][1], O[qj][nt], 0, 0, 0);
    }
  }
}

__global__ __launch_bounds__(256, 2) void attn_mfma(
    const u16* __restrict__ Qb, const u16* __restrict__ Kb,
    const u16* __restrict__ Vtb, u16* __restrict__ Yb) {
  __shared__ __attribute__((aligned(16))) u16 Ks[64 * 64];
  __shared__ __attribute__((aligned(16))) u16 Vts[64 * 64];
  __shared__ __attribute__((aligned(16))) u32 Ps[4][32 * 36];

  int bid = blockIdx.x;
  int bh = bid & 7;             // b*4+hkv -> same XCD for all its q-tiles
  int qt32 = bid >> 3;
  int hkv = bh & 3;
  int b = bh >> 2;
  int q0 = qt32 * 32;
  int tid = threadIdx.x;
  int g = tid >> 6;
  int lane = tid & 63;
  int quad = lane >> 4;
  int l16 = lane & 15;

  // Q B-frags (n = q, k = quad*8+j), 2 q-subtiles x 2 K-halves
  short8 QB[2][2];
#pragma unroll
  for (int qj = 0; qj < 2; qj++) {
    const u16* qb = Qb +
        ((long)(((b * 4 + hkv) * 4 + g) * Tq + q0 + qj * 16 + l16)) * 64 +
        quad * 8;
    QB[qj][0] = *(const short8*)(qb);
    QB[qj][1] = *(const short8*)(qb + 32);
  }

  f32x4 O[2][4];
#pragma unroll
  for (int qj = 0; qj < 2; qj++)
#pragma unroll
    for (int nt = 0; nt < 4; nt++) O[qj][nt] = (f32x4){0.f, 0.f, 0.f, 0.f};
  float lsum[2] = {0.f, 0.f};

  int lo = q0 - (WSq - 1);
  int st = (lo < 0 ? 0 : lo) >> 6;
  int et = (q0 + 31) >> 6;

  const u16* Kbase = Kb + ((long)((b * 4 + hkv) * Tq)) * 64;
  const u16* Vbase = Vtb + ((long)((b * 4 + hkv) * 64)) * Tq;
  u32* myPs = &Ps[g][0];

  int rowoffK[2], rowoffV[2];
#pragma unroll
  for (int i = 0; i < 2; i++) {
    int s = i * 256 + tid;
    int row = s >> 3, gl = s & 7;
    rowoffK[i] = row * 64 + (gl ^ (row & 7)) * 8;
    rowoffV[i] = row * Tq + (gl ^ (row & 7)) * 8;
  }

  for (int kt = st; kt <= et; kt++) {
    int k0 = kt * 64;
    __syncthreads();
#pragma unroll
    for (int i = 0; i < 2; i++) {
      gl_lds16(Kbase + (long)k0 * 64 + rowoffK[i], &Ks[(i * 256 + g * 64) * 8]);
      gl_lds16(Vbase + k0 + rowoffV[i], &Vts[(i * 256 + g * 64) * 8]);
    }
    __syncthreads();

    bool needC = (k0 > q0 - 63);          // exists kpos > qpos
    bool needW = (k0 < q0 - 992);         // exists kpos < qpos-1023
    if (needC || needW)
      attn_tile32<true>(k0, q0, quad, l16, Ks, Vts, myPs, QB, O, lsum);
    else
      attn_tile32<false>(k0, q0, quad, l16, Ks, Vts, myPs, QB, O, lsum);
  }

  // reduce l across quads; lane's lsum[qj] holds q = qj*16+l16 partial
#pragma unroll
  for (int qj = 0; qj < 2; qj++) {
    lsum[qj] += __shfl_xor(lsum[qj], 16);
    lsum[qj] += __shfl_xor(lsum[qj], 32);
  }

  int h = hkv * 4 + g;
#pragma unroll
  for (int qj = 0; qj < 2; qj++) {
    float invl[4];
#pragma unroll
    for (int r = 0; r < 4; r++) invl[r] = 1.f / __shfl(lsum[qj], quad * 4 + r);
#pragma unroll
    for (int nt = 0; nt < 4; nt++)
#pragma unroll
      for (int r = 0; r < 4; r++)
        Yb[((long)(b * Tq + q0 + qj * 16 + quad * 4 + r)) * 1024 + h * 64 +
           nt * 16 + l16] = f2bf(O[qj][nt][r] * invl[r]);
  }
}

// ---------------------------------------------------------------------------
extern "C" void kernel_launch(void* const* d_in, const int* in_sizes, int n_in,
                              void* d_out, int out_size, void* d_ws,
                              size_t ws_size, hipStream_t stream) {
  const float* x     = (const float*)d_in[0];
  const float* ve    = (const float*)d_in[1];
  const float* cosp  = (const float*)d_in[2];
  const float* sinp  = (const float*)d_in[3];
  const float* Wq    = (const float*)d_in[4];
  const float* Wk    = (const float*)d_in[5];
  const float* Wv    = (const float*)d_in[6];
  const float* Wproj = (const float*)d_in[7];
  const float* Wg    = (const float*)d_in[8];

  // workspace layout (38.8 MB), aliasing dead buffers:
  //  [ 0        ,  8,388,608)  xb bf16        -> Qb bf16 (after qkv gemm)
  //  [ 8,388,608, 11,534,336)  WqkvT bf16     -> Kb bf16 (after qkv gemm)
  //  [11,534,336, 13,631,488)  WprojT bf16    (persistent)
  //  [13,631,488, 26,214,400)  QKVb bf16 [4096][1536]
  //  [26,214,400, 28,311,552)  Vb bf16
  //  [28,311,552, 30,408,704)  Vtb bf16
  //  [30,408,704, 38,797,312)  Yb bf16
  char* base = (char*)d_ws;
  u16* xb     = (u16*)(base);
  u16* Qb     = xb;
  u16* WqkvT  = (u16*)(base + 8388608);
  u16* Kb     = WqkvT;
  u16* WprojT = (u16*)(base + 11534336);
  u16* QKVb   = (u16*)(base + 13631488);
  u16* Vb     = (u16*)(base + 26214400);
  u16* Vtb    = (u16*)(base + 28311552);
  u16* Yb     = (u16*)(base + 30408704);
  float* out = (float*)d_out;

  cast_bf16<<<2048, 256, 0, stream>>>(x, xb);
  wtrans_all<<<dim3(40, 16), 256, 0, stream>>>(Wq, Wk, Wv, Wproj, WqkvT,
                                               WprojT);
  gemm_bt<true><<<dim3(12, 64), 256, 0, stream>>>(xb, WqkvT, QKVb, 4096, 1536,
                                                  1024);
  postproc<<<Bq * Tq, 256, 0, stream>>>(x, ve, cosp, sinp, Wg, QKVb, Qb, Kb,
                                        Vb);
  vtrans<<<dim3(32, 8), 256, 0, stream>>>(Vb, Vtb);
  attn_mfma<<<512, 256, 0, stream>>>(Qb, Kb, Vtb, Yb);
  gemm_bt<false><<<dim3(8, 64), 256, 0, stream>>>(Yb, WprojT, out, 4096, 1024,
                                                  1024);
}

// Round 6
// 183.197 us; speedup vs baseline: 5.9256x; 1.0166x over previous
//
#include <hip/hip_runtime.h>
#include <hip/hip_bf16.h>

// Problem constants
#define Bq 2
#define Tq 2048
#define Cq 1024
#define Hq 16
#define HKVq 4
#define HDq 64
#define Gq 4
#define WSq 1024
#define GATE_CHq 32

typedef __attribute__((ext_vector_type(8))) short short8;   // 8 bf16 (4 VGPRs)
typedef __attribute__((ext_vector_type(4))) float f32x4;    // MFMA C/D frag
typedef __attribute__((ext_vector_type(2))) unsigned int u32x2;
typedef unsigned int u32;
typedef unsigned short u16;

#if __has_builtin(__builtin_amdgcn_exp2f)
#define EXP2(x) __builtin_amdgcn_exp2f(x)
#else
#define EXP2(x) exp2f(x)
#endif

__device__ __forceinline__ u16 f2bf(float f) {
  u32 u = __float_as_uint(f);
  u32 r = (u + 0x7FFFu + ((u >> 16) & 1u)) >> 16;  // RNE
  return (u16)r;
}
__device__ __forceinline__ float bf2f(u16 u) {
  return __uint_as_float(((u32)u) << 16);
}

__device__ __forceinline__ void gl_lds16(const u16* g, u16* l) {
  __builtin_amdgcn_global_load_lds(
      (const u32 __attribute__((address_space(1)))*)g,
      (u32 __attribute__((address_space(3)))*)l, 16, 0, 0);
}

// ---------------------------------------------------------------------------
// bf16 MFMA GEMM: C[M][N] = A[M][K] @ Bt[N][K]^T. 64x128 tile, BK=64
// (16 k-iters at K=1024: half the barriers of BK=32). 256 threads
// (4 waves, 32x64 each). global_load_lds staging, granule-XOR swizzle
// (phys = glog ^ (row&7)); all frag ds_read_b128 2-way (free).
// ---------------------------------------------------------------------------
template <bool BF16OUT>
__global__ __launch_bounds__(256) void gemm_bt(
    const u16* __restrict__ A, const u16* __restrict__ Bt,
    void* __restrict__ Cv, int M, int N, int K) {
  __shared__ __attribute__((aligned(16))) u16 As[64 * 64];    // 8 KB
  __shared__ __attribute__((aligned(16))) u16 Bs[128 * 64];   // 16 KB

  const int bm0 = blockIdx.y * 64, bn0 = blockIdx.x * 128;
  const int tid = threadIdx.x;
  const int w = tid >> 6, lane = tid & 63;
  const int wm = (w >> 1) * 32, wn = (w & 1) * 64;
  const int quad = lane >> 4, l16 = lane & 15;

  f32x4 acc[2][4];
#pragma unroll
  for (int mt = 0; mt < 2; mt++)
#pragma unroll
    for (int nt = 0; nt < 4; nt++) acc[mt][nt] = (f32x4){0.f, 0.f, 0.f, 0.f};

  // staging: slot s -> row m = s>>3 (8 granules of 16B per 64-elem row),
  // phys granule s&7 holds logical (s&7)^(m&7).
  int goffA[2], goffB[4];
#pragma unroll
  for (int i = 0; i < 2; i++) {
    int s = i * 256 + tid;
    int m = s >> 3, gp = s & 7;
    goffA[i] = m * K + (gp ^ (m & 7)) * 8;
  }
#pragma unroll
  for (int i = 0; i < 4; i++) {
    int s = i * 256 + tid;
    int m = s >> 3, gp = s & 7;
    goffB[i] = m * K + (gp ^ (m & 7)) * 8;
  }
  const u16* Ab = A + (long)bm0 * K;
  const u16* Bb = Bt + (long)bn0 * K;

  for (int k0 = 0; k0 < K; k0 += 64) {
    __syncthreads();
#pragma unroll
    for (int i = 0; i < 2; i++)
      gl_lds16(Ab + goffA[i] + k0, &As[(i * 256 + w * 64) * 8]);
#pragma unroll
    for (int i = 0; i < 4; i++)
      gl_lds16(Bb + goffB[i] + k0, &Bs[(i * 256 + w * 64) * 8]);
    __syncthreads();

#pragma unroll
    for (int ks = 0; ks < 2; ks++) {
      short8 af[2], bf[4];
#pragma unroll
      for (int mt = 0; mt < 2; mt++) {
        int ml = wm + mt * 16 + l16;
        af[mt] = *(const short8*)&As[ml * 64 + (((ks * 4 + quad) ^ (ml & 7)) * 8)];
      }
#pragma unroll
      for (int nt = 0; nt < 4; nt++) {
        int nl = wn + nt * 16 + l16;
        bf[nt] = *(const short8*)&Bs[nl * 64 + (((ks * 4 + quad) ^ (nl & 7)) * 8)];
      }
#pragma unroll
      for (int mt = 0; mt < 2; mt++)
#pragma unroll
        for (int nt = 0; nt < 4; nt++)
          acc[mt][nt] = __builtin_amdgcn_mfma_f32_16x16x32_bf16(
              af[mt], bf[nt], acc[mt][nt], 0, 0, 0);
    }
  }

#pragma unroll
  for (int mt = 0; mt < 2; mt++)
#pragma unroll
    for (int nt = 0; nt < 4; nt++) {
      int row0 = bm0 + wm + mt * 16 + quad * 4;
      int col = bn0 + wn + nt * 16 + l16;
#pragma unroll
      for (int r = 0; r < 4; r++) {
        if (BF16OUT)
          ((u16*)Cv)[(long)(row0 + r) * N + col] = f2bf(acc[mt][nt][r]);
        else
          ((float*)Cv)[(long)(row0 + r) * N + col] = acc[mt][nt][r];
      }
    }
}

// ---------------------------------------------------------------------------
// prep: x -> bf16 cast (blocks 0..2047) + all weight transposes (2048..2687)
// ---------------------------------------------------------------------------
__global__ __launch_bounds__(256) void prep(
    const float* __restrict__ x, u16* __restrict__ xb,
    const float* __restrict__ Wq, const float* __restrict__ Wk,
    const float* __restrict__ Wv, const float* __restrict__ Wproj,
    u16* __restrict__ Dqkv, u16* __restrict__ Dproj) {
  __shared__ float tile[64][65];
  int bx = blockIdx.x;
  int tid = threadIdx.x;
  if (bx < 2048) {
    int i = (bx * 256 + tid) * 8;
    float4 a = *(const float4*)(x + i);
    float4 b = *(const float4*)(x + i + 4);
    union { short8 v; u16 u[8]; } o;
    o.u[0] = f2bf(a.x); o.u[1] = f2bf(a.y); o.u[2] = f2bf(a.z); o.u[3] = f2bf(a.w);
    o.u[4] = f2bf(b.x); o.u[5] = f2bf(b.y); o.u[6] = f2bf(b.z); o.u[7] = f2bf(b.w);
    *(short8*)(xb + i) = o.v;
    return;
  }
  int wb = bx - 2048;             // 0..639
  int obx = wb >> 4;              // 0..39
  int k0 = (wb & 15) * 64;
  const float* S;
  u16* Dst;
  int N, nb;
  if (obx < 16)      { S = Wq;    N = 1024; nb = obx;      Dst = Dqkv; }
  else if (obx < 20) { S = Wk;    N = 256;  nb = obx - 16; Dst = Dqkv + 1024 * 1024; }
  else if (obx < 24) { S = Wv;    N = 256;  nb = obx - 20; Dst = Dqkv + 1280 * 1024; }
  else               { S = Wproj; N = 1024; nb = obx - 24; Dst = Dproj; }
  int n0 = nb * 64;
#pragma unroll
  for (int i = 0; i < 16; i++) {
    int idx = i * 256 + tid;
    int kl = idx >> 6, nl = idx & 63;
    tile[kl][nl] = S[(long)(k0 + kl) * N + n0 + nl];
  }
  __syncthreads();
#pragma unroll
  for (int i = 0; i < 16; i++) {
    int idx = i * 256 + tid;
    int nl = idx >> 6, kl = idx & 63;
    Dst[(long)(n0 + nl) * 1024 + k0 + kl] = f2bf(tile[kl][nl]);
  }
}

// ---------------------------------------------------------------------------
// postproc2: gate+ve into V, RoPE+RMSNorm on Q,K, AND V-transpose — fused.
// Block = (t-tile 64, bh); wave w handles t = t0 + tt*4 + w. V rows collect
// in an LDS tile, transposed coalesced write to Vtb at the end.
//   Qb[bh*4+g][t][d], Kb[bh][t][d], Vtb[bh][d][t]
// ---------------------------------------------------------------------------
__device__ __forceinline__ float rope_rms(float u, int lane, float c, float s) {
  float up = __shfl_xor(u, 32);
  float r = (lane < 32) ? (u * c + up * s) : (u * c - up * s);
  float sum = r * r;
#pragma unroll
  for (int off = 32; off >= 1; off >>= 1) sum += __shfl_xor(sum, off);
  return r * rsqrtf(sum * (1.f / 64.f) + 1.1920928955078125e-07f);
}

__global__ __launch_bounds__(256) void postproc2(
    const float* __restrict__ x, const float* __restrict__ ve,
    const float* __restrict__ cosp, const float* __restrict__ sinp,
    const float* __restrict__ Wg, const u16* __restrict__ QKV,
    u16* __restrict__ Qb, u16* __restrict__ Kb, u16* __restrict__ Vtb) {
  __shared__ u16 vt[64][70];      // pad 70: transpose reads 2-way conflict
  int bh = blockIdx.y;            // b*4 + hkv
  int b = bh >> 2, hkv = bh & 3;
  int t0 = blockIdx.x * 64;
  int tid = threadIdx.x;
  int w = tid >> 6, lane = tid & 63;

  for (int tt = 0; tt < 16; tt++) {
    int tl = tt * 4 + w;
    int t = t0 + tl;
    long bt = (long)b * Tq + t;
    const u16* row = QKV + bt * 1536;
    float c = cosp[t * 32 + (lane & 31)];
    float s = sinp[t * 32 + (lane & 31)];

    float pg = 0.f;
    if (lane < 32) pg = x[bt * Cq + lane] * Wg[lane * HKVq + hkv];
#pragma unroll
    for (int off = 16; off >= 1; off >>= 1) pg += __shfl_xor(pg, off);
    float gate = 2.f / (1.f + expf(-__shfl(pg, 0)));

    float v = bf2f(row[1280 + hkv * 64 + lane]) +
              gate * ve[bt * 256 + hkv * 64 + lane];
    vt[tl][lane] = f2bf(v);

    float kv = rope_rms(bf2f(row[1024 + hkv * 64 + lane]), lane, c, s);
    Kb[((long)bh * Tq + t) * 64 + lane] = f2bf(kv);

#pragma unroll
    for (int g = 0; g < 4; g++) {
      float q = rope_rms(bf2f(row[(hkv * 4 + g) * 64 + lane]), lane, c, s);
      Qb[((long)(bh * 4 + g) * Tq + t) * 64 + lane] = f2bf(q);
    }
  }
  __syncthreads();
#pragma unroll
  for (int i = 0; i < 16; i++) {
    int idx = i * 256 + tid;
    int d = idx >> 6, tl = idx & 63;
    Vtb[(long)bh * 64 * Tq + (long)d * Tq + t0 + tl] = vt[tl][d];
  }
}

// ---------------------------------------------------------------------------
// MFMA flash attention v4: q-tile 32, K-tile 128 (two independent 64-key
// halves per barrier -> ILP across the serial chain), fixed-max softmax.
// Block = (b,hkv,qt32), 512 blocks (2/CU); 4 waves = 4 GQA heads.
// ---------------------------------------------------------------------------
#define CEXP 0.18033688011112042f   // 0.125 * log2(e)
#define CEXP8 1.4426950408889634f   // 8 * 0.125 * log2(e)

template <bool MASK>
__device__ __forceinline__ void attn_half(
    int k0h, int key_base, int vg_base, int q0, int quad, int l16,
    const u16* __restrict__ Ks, const u16* __restrict__ Vts,
    u32* __restrict__ myPs, const short8 (&QB)[2][2], f32x4 (&O)[2][4],
    float (&lsum)[2]) {
  // S^T = K·Q^T : A = K-frag (m=key), B = Q-frag (n=q)
  f32x4 S4[4][2];
#pragma unroll
  for (int kt4 = 0; kt4 < 4; kt4++) {
    int key = key_base + kt4 * 16 + l16;
    short8 kb0 = *(const short8*)(&Ks[key * 64 + ((quad ^ (key & 7)) * 8)]);
    short8 kb1 = *(const short8*)(&Ks[key * 64 + (((4 + quad) ^ (key & 7)) * 8)]);
#pragma unroll
    for (int qj = 0; qj < 2; qj++) {
      f32x4 acc = (f32x4){0.f, 0.f, 0.f, 0.f};
      acc = __builtin_amdgcn_mfma_f32_16x16x32_bf16(kb0, QB[qj][0], acc, 0, 0, 0);
      acc = __builtin_amdgcn_mfma_f32_16x16x32_bf16(kb1, QB[qj][1], acc, 0, 0, 0);
      S4[kt4][qj] = acc;
    }
  }

  // p = exp2(s*CEXP - CEXP8); pack bf16 pairs -> per-(wave,half) LDS
#pragma unroll
  for (int kt4 = 0; kt4 < 4; kt4++)
#pragma unroll
    for (int qj = 0; qj < 2; qj++) {
      float Pv[4];
#pragma unroll
      for (int r = 0; r < 4; r++) {
        float sv = S4[kt4][qj][r];
        if (MASK) {
          int kpos = k0h + kt4 * 16 + quad * 4 + r;
          int qpos = q0 + qj * 16 + l16;
          bool valid = (kpos <= qpos) && (kpos >= qpos - (WSq - 1));
          sv = valid ? sv : -1e30f;
        }
        float p = EXP2(__builtin_fmaf(sv, CEXP, -CEXP8));
        Pv[r] = p;
        lsum[qj] += p;
      }
      u32x2 pk;
#pragma unroll
      for (int rp = 0; rp < 2; rp++) {
        u32 lo = __float_as_uint(Pv[2 * rp]) + 0x8000u;
        u32 hi = __float_as_uint(Pv[2 * rp + 1]) + 0x8000u;
        pk[rp] = __builtin_amdgcn_perm(hi, lo, 0x07060302u);
      }
      *(u32x2*)(&myPs[(qj * 16 + l16) * 36 + kt4 * 8 + quad * 2]) = pk;
    }

  // V B-frags (n=d, k=key within this half)
  short8 vb[4][2];
#pragma unroll
  for (int nt = 0; nt < 4; nt++) {
    int d = nt * 16 + l16;
    vb[nt][0] = *(const short8*)(&Vts[d * 128 + (((vg_base + quad) ^ (d & 7)) * 8)]);
    vb[nt][1] =
        *(const short8*)(&Vts[d * 128 + (((vg_base + 4 + quad) ^ (d & 7)) * 8)]);
  }

  // O += P·V : A = P (m=q, k=key)
#pragma unroll
  for (int qj = 0; qj < 2; qj++) {
    const u32* prow = &myPs[(qj * 16 + l16) * 36];
    short8 pa0 = *(const short8*)(prow + quad * 4);
    short8 pa1 = *(const short8*)(prow + 16 + quad * 4);
#pragma unroll
    for (int nt = 0; nt < 4; nt++) {
      O[qj][nt] =
          __builtin_amdgcn_mfma_f32_16x16x32_bf16(pa0, vb[nt][0], O[qj][nt], 0, 0, 0);
      O[qj][nt] =
          __builtin_amdgcn_mfma_f32_16x16x32_bf16(pa1, vb[nt][1], O[qj][nt], 0, 0, 0);
    }
  }
}

__global__ __launch_bounds__(256, 2) void attn_mfma(
    const u16* __restrict__ Qb, const u16* __restrict__ Kb,
    const u16* __restrict__ Vtb, u16* __restrict__ Yb) {
  __shared__ __attribute__((aligned(16))) u16 Ks[128 * 64];    // 16 KB
  __shared__ __attribute__((aligned(16))) u16 Vts[64 * 128];   // 16 KB
  __shared__ __attribute__((aligned(16))) u32 Ps[4][2][32 * 36];  // 36 KB

  int bid = blockIdx.x;
  int bh = bid & 7;             // b*4+hkv -> XCD L2 locality
  int qt32 = bid >> 3;
  int hkv = bh & 3;
  int b = bh >> 2;
  int q0 = qt32 * 32;
  int tid = threadIdx.x;
  int g = tid >> 6;
  int lane = tid & 63;
  int quad = lane >> 4;
  int l16 = lane & 15;

  // Q B-frags (n = q, k = quad*8+j), 2 q-subtiles x 2 K-halves
  short8 QB[2][2];
#pragma unroll
  for (int qj = 0; qj < 2; qj++) {
    const u16* qb =
        Qb + ((long)((bh * 4 + g) * Tq + q0 + qj * 16 + l16)) * 64 + quad * 8;
    QB[qj][0] = *(const short8*)(qb);
    QB[qj][1] = *(const short8*)(qb + 32);
  }

  f32x4 O[2][4];
#pragma unroll
  for (int qj = 0; qj < 2; qj++)
#pragma unroll
    for (int nt = 0; nt < 4; nt++) O[qj][nt] = (f32x4){0.f, 0.f, 0.f, 0.f};
  float lsum[2] = {0.f, 0.f};

  int lo = q0 - (WSq - 1);
  int st = (lo < 0 ? 0 : lo) >> 7;
  int et = (q0 + 31) >> 7;

  const u16* Kbase = Kb + ((long)bh * Tq) * 64;
  const u16* Vbase = Vtb + ((long)bh * 64) * Tq;

  // staging offsets: K tile slot s: key=s>>3, gran=s&7; V tile: d=s>>4, kg=s&15
  int rowoffK[4], rowoffV[4];
#pragma unroll
  for (int i = 0; i < 4; i++) {
    int s = i * 256 + tid;
    int kr = s >> 3, kgp = s & 7;
    rowoffK[i] = kr * 64 + (kgp ^ (kr & 7)) * 8;
    int d = s >> 4, vgp = s & 15;
    rowoffV[i] = d * Tq + (vgp ^ (d & 7)) * 8;
  }

  for (int kt = st; kt <= et; kt++) {
    int k0 = kt << 7;
    __syncthreads();
#pragma unroll
    for (int i = 0; i < 4; i++) {
      gl_lds16(Kbase + (long)k0 * 64 + rowoffK[i], &Ks[(i * 256 + g * 64) * 8]);
      gl_lds16(Vbase + k0 + rowoffV[i], &Vts[(i * 256 + g * 64) * 8]);
    }
    __syncthreads();

    bool needC = (k0 + 127 > q0);
    bool needW = (k0 < q0 - 992);
    if (needC || needW) {
      attn_half<true>(k0, 0, 0, q0, quad, l16, Ks, Vts, &Ps[g][0][0], QB, O, lsum);
      attn_half<true>(k0 + 64, 64, 8, q0, quad, l16, Ks, Vts, &Ps[g][1][0], QB,
                      O, lsum);
    } else {
      attn_half<false>(k0, 0, 0, q0, quad, l16, Ks, Vts, &Ps[g][0][0], QB, O,
                       lsum);
      attn_half<false>(k0 + 64, 64, 8, q0, quad, l16, Ks, Vts, &Ps[g][1][0], QB,
                       O, lsum);
    }
  }

  // reduce l across quads; lane's lsum[qj] holds q = qj*16+l16 partial
#pragma unroll
  for (int qj = 0; qj < 2; qj++) {
    lsum[qj] += __shfl_xor(lsum[qj], 16);
    lsum[qj] += __shfl_xor(lsum[qj], 32);
  }

  int h = hkv * 4 + g;
#pragma unroll
  for (int qj = 0; qj < 2; qj++) {
    float invl[4];
#pragma unroll
    for (int r = 0; r < 4; r++) invl[r] = 1.f / __shfl(lsum[qj], quad * 4 + r);
#pragma unroll
    for (int nt = 0; nt < 4; nt++)
#pragma unroll
      for (int r = 0; r < 4; r++)
        Yb[((long)(b * Tq + q0 + qj * 16 + quad * 4 + r)) * 1024 + h * 64 +
           nt * 16 + l16] = f2bf(O[qj][nt][r] * invl[r]);
  }
}

// ---------------------------------------------------------------------------
extern "C" void kernel_launch(void* const* d_in, const int* in_sizes, int n_in,
                              void* d_out, int out_size, void* d_ws,
                              size_t ws_size, hipStream_t stream) {
  const float* x     = (const float*)d_in[0];
  const float* ve    = (const float*)d_in[1];
  const float* cosp  = (const float*)d_in[2];
  const float* sinp  = (const float*)d_in[3];
  const float* Wq    = (const float*)d_in[4];
  const float* Wk    = (const float*)d_in[5];
  const float* Wv    = (const float*)d_in[6];
  const float* Wproj = (const float*)d_in[7];
  const float* Wg    = (const float*)d_in[8];

  // workspace layout, aliasing dead buffers:
  //  [ 0        ,  8,388,608)  xb bf16        -> Qb bf16 (after qkv gemm)
  //  [ 8,388,608, 11,534,336)  WqkvT bf16     -> Kb bf16 (after qkv gemm)
  //  [11,534,336, 13,631,488)  WprojT bf16    (persistent)
  //  [13,631,488, 26,214,400)  QKVb bf16 [4096][1536]
  //  [26,214,400, 28,311,552)  Vtb bf16
  //  [28,311,552, 36,700,160)  Yb bf16
  char* base = (char*)d_ws;
  u16* xb     = (u16*)(base);
  u16* Qb     = xb;
  u16* WqkvT  = (u16*)(base + 8388608);
  u16* Kb     = WqkvT;
  u16* WprojT = (u16*)(base + 11534336);
  u16* QKVb   = (u16*)(base + 13631488);
  u16* Vtb    = (u16*)(base + 26214400);
  u16* Yb     = (u16*)(base + 28311552);
  float* out = (float*)d_out;

  prep<<<2688, 256, 0, stream>>>(x, xb, Wq, Wk, Wv, Wproj, WqkvT, WprojT);
  gemm_bt<true><<<dim3(12, 64), 256, 0, stream>>>(xb, WqkvT, QKVb, 4096, 1536,
                                                  1024);
  postproc2<<<dim3(32, 8), 256, 0, stream>>>(x, ve, cosp, sinp, Wg, QKVb, Qb,
                                             Kb, Vtb);
  attn_mfma<<<512, 256, 0, stream>>>(Qb, Kb, Vtb, Yb);
  gemm_bt<false><<<dim3(8, 64), 256, 0, stream>>>(Yb, WprojT, out, 4096, 1024,
                                                  1024);
}

// Round 7
// 162.184 us; speedup vs baseline: 6.6933x; 1.1296x over previous
//
#include <hip/hip_runtime.h>
#include <hip/hip_bf16.h>

// Problem constants
#define Bq 2
#define Tq 2048
#define Cq 1024
#define Hq 16
#define HKVq 4
#define HDq 64
#define Gq 4
#define WSq 1024
#define GATE_CHq 32

typedef __attribute__((ext_vector_type(8))) short short8;   // 8 bf16 (4 VGPRs)
typedef __attribute__((ext_vector_type(4))) float f32x4;    // MFMA C/D frag
typedef __attribute__((ext_vector_type(2))) unsigned int u32x2;
typedef unsigned int u32;
typedef unsigned short u16;

#if __has_builtin(__builtin_amdgcn_exp2f)
#define EXP2(x) __builtin_amdgcn_exp2f(x)
#else
#define EXP2(x) exp2f(x)
#endif

__device__ __forceinline__ u16 f2bf(float f) {
  u32 u = __float_as_uint(f);
  u32 r = (u + 0x7FFFu + ((u >> 16) & 1u)) >> 16;  // RNE
  return (u16)r;
}
__device__ __forceinline__ float bf2f(u16 u) {
  return __uint_as_float(((u32)u) << 16);
}

__device__ __forceinline__ void gl_lds16(const u16* g, u16* l) {
  __builtin_amdgcn_global_load_lds(
      (const u32 __attribute__((address_space(1)))*)g,
      (u32 __attribute__((address_space(3)))*)l, 16, 0, 0);
}

// ---------------------------------------------------------------------------
// Fused QKV GEMM + RoPE/RMSNorm/gate epilogue.
// C-tile 64x128 over A[4096][1024] @ WqkvT[1536][1024]^T, BK=64.
// bx 0..7: Q cols (wave's 64-col span = one head); 8..9: K; 10..11: V.
// Epilogue (in-register): Q/K rope+rms -> bf16 attention layout;
// V += gate*ve -> transposed bf16 (short4 along t).
// ---------------------------------------------------------------------------
__global__ __launch_bounds__(256) void qkv_gemm_fused(
    const u16* __restrict__ A, const u16* __restrict__ Bt,
    const float* __restrict__ ve, const float* __restrict__ cosp,
    const float* __restrict__ sinp, const float* __restrict__ gatebuf,
    u16* __restrict__ Qb, u16* __restrict__ Kb, u16* __restrict__ Vtb) {
  __shared__ __attribute__((aligned(16))) u16 As[64 * 64];    // 8 KB
  __shared__ __attribute__((aligned(16))) u16 Bs[128 * 64];   // 16 KB

  const int bx = blockIdx.x;
  const int bm0 = blockIdx.y * 64, bn0 = bx * 128;
  const int tid = threadIdx.x;
  const int w = tid >> 6, lane = tid & 63;
  const int wm = (w >> 1) * 32, wn = (w & 1) * 64;
  const int quad = lane >> 4, l16 = lane & 15;
  const int K = 1024;

  f32x4 acc[2][4];
#pragma unroll
  for (int mt = 0; mt < 2; mt++)
#pragma unroll
    for (int nt = 0; nt < 4; nt++) acc[mt][nt] = (f32x4){0.f, 0.f, 0.f, 0.f};

  int goffA[2], goffB[4];
#pragma unroll
  for (int i = 0; i < 2; i++) {
    int s = i * 256 + tid;
    int m = s >> 3, gp = s & 7;
    goffA[i] = m * K + (gp ^ (m & 7)) * 8;
  }
#pragma unroll
  for (int i = 0; i < 4; i++) {
    int s = i * 256 + tid;
    int m = s >> 3, gp = s & 7;
    goffB[i] = m * K + (gp ^ (m & 7)) * 8;
  }
  const u16* Ab = A + (long)bm0 * K;
  const u16* Bb = Bt + (long)bn0 * K;

  for (int k0 = 0; k0 < K; k0 += 64) {
    __syncthreads();
#pragma unroll
    for (int i = 0; i < 2; i++)
      gl_lds16(Ab + goffA[i] + k0, &As[(i * 256 + w * 64) * 8]);
#pragma unroll
    for (int i = 0; i < 4; i++)
      gl_lds16(Bb + goffB[i] + k0, &Bs[(i * 256 + w * 64) * 8]);
    __syncthreads();

#pragma unroll
    for (int ks = 0; ks < 2; ks++) {
      short8 af[2], bf[4];
#pragma unroll
      for (int mt = 0; mt < 2; mt++) {
        int ml = wm + mt * 16 + l16;
        af[mt] = *(const short8*)&As[ml * 64 + (((ks * 4 + quad) ^ (ml & 7)) * 8)];
      }
#pragma unroll
      for (int nt = 0; nt < 4; nt++) {
        int nl = wn + nt * 16 + l16;
        bf[nt] = *(const short8*)&Bs[nl * 64 + (((ks * 4 + quad) ^ (nl & 7)) * 8)];
      }
#pragma unroll
      for (int mt = 0; mt < 2; mt++)
#pragma unroll
        for (int nt = 0; nt < 4; nt++)
          acc[mt][nt] = __builtin_amdgcn_mfma_f32_16x16x32_bf16(
              af[mt], bf[nt], acc[mt][nt], 0, 0, 0);
    }
  }

  // ---- fused epilogue ----
  const int b = bm0 >> 11;                 // batch
  const int tseq0 = (bm0 & 2047) + wm;     // sequence-local t base of this wave

  if (bx < 10) {
    // Q (bx<8) or K: RoPE + RMSNorm, bf16 store in attention layout.
    u16* Dst;
    if (bx < 8) {
      int hh = bx * 2 + (w & 1);           // global q-head
      int hkv = hh >> 2, g = hh & 3;
      Dst = Qb + ((long)((b * 4 + hkv) * 4 + g) * Tq) * 64;
    } else {
      int kk = (bx - 8) * 2 + (w & 1);     // kv head
      Dst = Kb + ((long)(b * 4 + kk) * Tq) * 64;
    }
#pragma unroll
    for (int mt = 0; mt < 2; mt++) {
#pragma unroll
      for (int r = 0; r < 4; r++) {
        int t = tseq0 + mt * 16 + quad * 4 + r;
        float c0 = cosp[t * 32 + l16];
        float s0 = sinp[t * 32 + l16];
        float c1 = cosp[t * 32 + 16 + l16];
        float s1 = sinp[t * 32 + 16 + l16];
        float a0 = acc[mt][0][r], a1 = acc[mt][1][r];
        float a2 = acc[mt][2][r], a3 = acc[mt][3][r];
        float rp0 = a0 * c0 + a2 * s0;
        float rp1 = a1 * c1 + a3 * s1;
        float rp2 = a2 * c0 - a0 * s0;
        float rp3 = a3 * c1 - a1 * s1;
        float ss = rp0 * rp0 + rp1 * rp1 + rp2 * rp2 + rp3 * rp3;
        ss += __shfl_xor(ss, 1);
        ss += __shfl_xor(ss, 2);
        ss += __shfl_xor(ss, 4);
        ss += __shfl_xor(ss, 8);
        float sc = rsqrtf(ss * (1.f / 64.f) + 1.1920928955078125e-07f);
        u16* drow = Dst + (long)t * 64;
        drow[l16] = f2bf(rp0 * sc);
        drow[16 + l16] = f2bf(rp1 * sc);
        drow[32 + l16] = f2bf(rp2 * sc);
        drow[48 + l16] = f2bf(rp3 * sc);
      }
    }
  } else {
    // V: val = acc + gate(b,t,kk) * ve[b,t,kk,d]; store transposed bf16.
    int kk = (bx - 10) * 2 + (w & 1);
    u16* Dst = Vtb + ((long)(b * 4 + kk) * 64) * Tq;
#pragma unroll
    for (int mt = 0; mt < 2; mt++) {
      float vals[4][4];  // [nt][r]
#pragma unroll
      for (int r = 0; r < 4; r++) {
        int t = tseq0 + mt * 16 + quad * 4 + r;
        long bt = (long)b * Tq + t;
        float gv = gatebuf[bt * 4 + kk];
        const float* verow = ve + bt * 256 + kk * 64;
#pragma unroll
        for (int nt = 0; nt < 4; nt++)
          vals[nt][r] = acc[mt][nt][r] + gv * verow[nt * 16 + l16];
      }
      int t0m = tseq0 + mt * 16 + quad * 4;
#pragma unroll
      for (int nt = 0; nt < 4; nt++) {
        int d = nt * 16 + l16;
        union { short4 v; u16 u[4]; } p;
#pragma unroll
        for (int r = 0; r < 4; r++) p.u[r] = f2bf(vals[nt][r]);
        *(short4*)(Dst + (long)d * Tq + t0m) = p.v;
      }
    }
  }
}

// ---------------------------------------------------------------------------
// proj GEMM (f32 out), 64x128 tile, BK=64 — same core as qkv, no epilogue.
// ---------------------------------------------------------------------------
__global__ __launch_bounds__(256) void gemm_proj(
    const u16* __restrict__ A, const u16* __restrict__ Bt,
    float* __restrict__ C, int M, int N, int K) {
  __shared__ __attribute__((aligned(16))) u16 As[64 * 64];
  __shared__ __attribute__((aligned(16))) u16 Bs[128 * 64];

  const int bm0 = blockIdx.y * 64, bn0 = blockIdx.x * 128;
  const int tid = threadIdx.x;
  const int w = tid >> 6, lane = tid & 63;
  const int wm = (w >> 1) * 32, wn = (w & 1) * 64;
  const int quad = lane >> 4, l16 = lane & 15;

  f32x4 acc[2][4];
#pragma unroll
  for (int mt = 0; mt < 2; mt++)
#pragma unroll
    for (int nt = 0; nt < 4; nt++) acc[mt][nt] = (f32x4){0.f, 0.f, 0.f, 0.f};

  int goffA[2], goffB[4];
#pragma unroll
  for (int i = 0; i < 2; i++) {
    int s = i * 256 + tid;
    int m = s >> 3, gp = s & 7;
    goffA[i] = m * K + (gp ^ (m & 7)) * 8;
  }
#pragma unroll
  for (int i = 0; i < 4; i++) {
    int s = i * 256 + tid;
    int m = s >> 3, gp = s & 7;
    goffB[i] = m * K + (gp ^ (m & 7)) * 8;
  }
  const u16* Ab = A + (long)bm0 * K;
  const u16* Bb = Bt + (long)bn0 * K;

  for (int k0 = 0; k0 < K; k0 += 64) {
    __syncthreads();
#pragma unroll
    for (int i = 0; i < 2; i++)
      gl_lds16(Ab + goffA[i] + k0, &As[(i * 256 + w * 64) * 8]);
#pragma unroll
    for (int i = 0; i < 4; i++)
      gl_lds16(Bb + goffB[i] + k0, &Bs[(i * 256 + w * 64) * 8]);
    __syncthreads();

#pragma unroll
    for (int ks = 0; ks < 2; ks++) {
      short8 af[2], bf[4];
#pragma unroll
      for (int mt = 0; mt < 2; mt++) {
        int ml = wm + mt * 16 + l16;
        af[mt] = *(const short8*)&As[ml * 64 + (((ks * 4 + quad) ^ (ml & 7)) * 8)];
      }
#pragma unroll
      for (int nt = 0; nt < 4; nt++) {
        int nl = wn + nt * 16 + l16;
        bf[nt] = *(const short8*)&Bs[nl * 64 + (((ks * 4 + quad) ^ (nl & 7)) * 8)];
      }
#pragma unroll
      for (int mt = 0; mt < 2; mt++)
#pragma unroll
        for (int nt = 0; nt < 4; nt++)
          acc[mt][nt] = __builtin_amdgcn_mfma_f32_16x16x32_bf16(
              af[mt], bf[nt], acc[mt][nt], 0, 0, 0);
    }
  }

#pragma unroll
  for (int mt = 0; mt < 2; mt++)
#pragma unroll
    for (int nt = 0; nt < 4; nt++) {
      int row0 = bm0 + wm + mt * 16 + quad * 4;
      int col = bn0 + wn + nt * 16 + l16;
#pragma unroll
      for (int r = 0; r < 4; r++)
        C[(long)(row0 + r) * N + col] = acc[mt][nt][r];
    }
}

// ---------------------------------------------------------------------------
// prep: x->bf16 (0..2047) + weight transposes (2048..2687) + gate (2688..2751)
// gate[bt][kk] = 2*sigmoid(sum_{i<32} x[bt][i]*Wg[i][kk])
// ---------------------------------------------------------------------------
__global__ __launch_bounds__(256) void prep(
    const float* __restrict__ x, u16* __restrict__ xb,
    const float* __restrict__ Wq, const float* __restrict__ Wk,
    const float* __restrict__ Wv, const float* __restrict__ Wproj,
    const float* __restrict__ Wg, u16* __restrict__ Dqkv,
    u16* __restrict__ Dproj, float* __restrict__ gatebuf) {
  __shared__ float tile[64][65];
  int bx = blockIdx.x;
  int tid = threadIdx.x;
  if (bx < 2048) {
    int i = (bx * 256 + tid) * 8;
    float4 a = *(const float4*)(x + i);
    float4 b = *(const float4*)(x + i + 4);
    union { short8 v; u16 u[8]; } o;
    o.u[0] = f2bf(a.x); o.u[1] = f2bf(a.y); o.u[2] = f2bf(a.z); o.u[3] = f2bf(a.w);
    o.u[4] = f2bf(b.x); o.u[5] = f2bf(b.y); o.u[6] = f2bf(b.z); o.u[7] = f2bf(b.w);
    *(short8*)(xb + i) = o.v;
    return;
  }
  if (bx >= 2688) {
    int p = (bx - 2688) * 256 + tid;   // 0..16383
    int bt = p >> 2, kk = p & 3;
    const float* xr = x + (long)bt * Cq;
    float dot = 0.f;
#pragma unroll
    for (int i = 0; i < GATE_CHq; i++) dot += xr[i] * Wg[i * HKVq + kk];
    gatebuf[p] = 2.f / (1.f + expf(-dot));
    return;
  }
  int wb = bx - 2048;             // 0..639
  int obx = wb >> 4;              // 0..39
  int k0 = (wb & 15) * 64;
  const float* S;
  u16* Dst;
  int N, nb;
  if (obx < 16)      { S = Wq;    N = 1024; nb = obx;      Dst = Dqkv; }
  else if (obx < 20) { S = Wk;    N = 256;  nb = obx - 16; Dst = Dqkv + 1024 * 1024; }
  else if (obx < 24) { S = Wv;    N = 256;  nb = obx - 20; Dst = Dqkv + 1280 * 1024; }
  else               { S = Wproj; N = 1024; nb = obx - 24; Dst = Dproj; }
  int n0 = nb * 64;
#pragma unroll
  for (int i = 0; i < 16; i++) {
    int idx = i * 256 + tid;
    int kl = idx >> 6, nl = idx & 63;
    tile[kl][nl] = S[(long)(k0 + kl) * N + n0 + nl];
  }
  __syncthreads();
#pragma unroll
  for (int i = 0; i < 16; i++) {
    int idx = i * 256 + tid;
    int nl = idx >> 6, kl = idx & 63;
    Dst[(long)(n0 + nl) * 1024 + k0 + kl] = f2bf(tile[kl][nl]);
  }
}

// ---------------------------------------------------------------------------
// MFMA flash attention v4 (round-6 structure): q-tile 32, K-tile 128,
// fixed-max softmax, S^T = K·Q^T, per-(wave,half) P LDS buffers.
// ---------------------------------------------------------------------------
#define CEXP 0.18033688011112042f   // 0.125 * log2(e)
#define CEXP8 1.4426950408889634f   // 8 * 0.125 * log2(e)

template <bool MASK>
__device__ __forceinline__ void attn_half(
    int k0h, int key_base, int vg_base, int q0, int quad, int l16,
    const u16* __restrict__ Ks, const u16* __restrict__ Vts,
    u32* __restrict__ myPs, const short8 (&QB)[2][2], f32x4 (&O)[2][4],
    float (&lsum)[2]) {
  f32x4 S4[4][2];
#pragma unroll
  for (int kt4 = 0; kt4 < 4; kt4++) {
    int key = key_base + kt4 * 16 + l16;
    short8 kb0 = *(const short8*)(&Ks[key * 64 + ((quad ^ (key & 7)) * 8)]);
    short8 kb1 = *(const short8*)(&Ks[key * 64 + (((4 + quad) ^ (key & 7)) * 8)]);
#pragma unroll
    for (int qj = 0; qj < 2; qj++) {
      f32x4 acc = (f32x4){0.f, 0.f, 0.f, 0.f};
      acc = __builtin_amdgcn_mfma_f32_16x16x32_bf16(kb0, QB[qj][0], acc, 0, 0, 0);
      acc = __builtin_amdgcn_mfma_f32_16x16x32_bf16(kb1, QB[qj][1], acc, 0, 0, 0);
      S4[kt4][qj] = acc;
    }
  }

#pragma unroll
  for (int kt4 = 0; kt4 < 4; kt4++)
#pragma unroll
    for (int qj = 0; qj < 2; qj++) {
      float Pv[4];
#pragma unroll
      for (int r = 0; r < 4; r++) {
        float sv = S4[kt4][qj][r];
        if (MASK) {
          int kpos = k0h + kt4 * 16 + quad * 4 + r;
          int qpos = q0 + qj * 16 + l16;
          bool valid = (kpos <= qpos) && (kpos >= qpos - (WSq - 1));
          sv = valid ? sv : -1e30f;
        }
        float p = EXP2(__builtin_fmaf(sv, CEXP, -CEXP8));
        Pv[r] = p;
        lsum[qj] += p;
      }
      u32x2 pk;
#pragma unroll
      for (int rp = 0; rp < 2; rp++) {
        u32 lo = __float_as_uint(Pv[2 * rp]) + 0x8000u;
        u32 hi = __float_as_uint(Pv[2 * rp + 1]) + 0x8000u;
        pk[rp] = __builtin_amdgcn_perm(hi, lo, 0x07060302u);
      }
      *(u32x2*)(&myPs[(qj * 16 + l16) * 36 + kt4 * 8 + quad * 2]) = pk;
    }

  short8 vb[4][2];
#pragma unroll
  for (int nt = 0; nt < 4; nt++) {
    int d = nt * 16 + l16;
    vb[nt][0] = *(const short8*)(&Vts[d * 128 + (((vg_base + quad) ^ (d & 7)) * 8)]);
    vb[nt][1] =
        *(const short8*)(&Vts[d * 128 + (((vg_base + 4 + quad) ^ (d & 7)) * 8)]);
  }

#pragma unroll
  for (int qj = 0; qj < 2; qj++) {
    const u32* prow = &myPs[(qj * 16 + l16) * 36];
    short8 pa0 = *(const short8*)(prow + quad * 4);
    short8 pa1 = *(const short8*)(prow + 16 + quad * 4);
#pragma unroll
    for (int nt = 0; nt < 4; nt++) {
      O[qj][nt] =
          __builtin_amdgcn_mfma_f32_16x16x32_bf16(pa0, vb[nt][0], O[qj][nt], 0, 0, 0);
      O[qj][nt] =
          __builtin_amdgcn_mfma_f32_16x16x32_bf16(pa1, vb[nt][1], O[qj][nt], 0, 0, 0);
    }
  }
}

__global__ __launch_bounds__(256, 2) void attn_mfma(
    const u16* __restrict__ Qb, const u16* __restrict__ Kb,
    const u16* __restrict__ Vtb, u16* __restrict__ Yb) {
  __shared__ __attribute__((aligned(16))) u16 Ks[128 * 64];
  __shared__ __attribute__((aligned(16))) u16 Vts[64 * 128];
  __shared__ __attribute__((aligned(16))) u32 Ps[4][2][32 * 36];

  int bid = blockIdx.x;
  int bh = bid & 7;
  int qt32 = bid >> 3;
  int hkv = bh & 3;
  int b = bh >> 2;
  int q0 = qt32 * 32;
  int tid = threadIdx.x;
  int g = tid >> 6;
  int lane = tid & 63;
  int quad = lane >> 4;
  int l16 = lane & 15;

  short8 QB[2][2];
#pragma unroll
  for (int qj = 0; qj < 2; qj++) {
    const u16* qb =
        Qb + ((long)((bh * 4 + g) * Tq + q0 + qj * 16 + l16)) * 64 + quad * 8;
    QB[qj][0] = *(const short8*)(qb);
    QB[qj][1] = *(const short8*)(qb + 32);
  }

  f32x4 O[2][4];
#pragma unroll
  for (int qj = 0; qj < 2; qj++)
#pragma unroll
    for (int nt = 0; nt < 4; nt++) O[qj][nt] = (f32x4){0.f, 0.f, 0.f, 0.f};
  float lsum[2] = {0.f, 0.f};

  int lo = q0 - (WSq - 1);
  int st = (lo < 0 ? 0 : lo) >> 7;
  int et = (q0 + 31) >> 7;

  const u16* Kbase = Kb + ((long)bh * Tq) * 64;
  const u16* Vbase = Vtb + ((long)bh * 64) * Tq;

  int rowoffK[4], rowoffV[4];
#pragma unroll
  for (int i = 0; i < 4; i++) {
    int s = i * 256 + tid;
    int kr = s >> 3, kgp = s & 7;
    rowoffK[i] = kr * 64 + (kgp ^ (kr & 7)) * 8;
    int d = s >> 4, vgp = s & 15;
    rowoffV[i] = d * Tq + (vgp ^ (d & 7)) * 8;
  }

  for (int kt = st; kt <= et; kt++) {
    int k0 = kt << 7;
    __syncthreads();
#pragma unroll
    for (int i = 0; i < 4; i++) {
      gl_lds16(Kbase + (long)k0 * 64 + rowoffK[i], &Ks[(i * 256 + g * 64) * 8]);
      gl_lds16(Vbase + k0 + rowoffV[i], &Vts[(i * 256 + g * 64) * 8]);
    }
    __syncthreads();

    bool needC = (k0 + 127 > q0);
    bool needW = (k0 < q0 - 992);
    if (needC || needW) {
      attn_half<true>(k0, 0, 0, q0, quad, l16, Ks, Vts, &Ps[g][0][0], QB, O, lsum);
      attn_half<true>(k0 + 64, 64, 8, q0, quad, l16, Ks, Vts, &Ps[g][1][0], QB,
                      O, lsum);
    } else {
      attn_half<false>(k0, 0, 0, q0, quad, l16, Ks, Vts, &Ps[g][0][0], QB, O,
                       lsum);
      attn_half<false>(k0 + 64, 64, 8, q0, quad, l16, Ks, Vts, &Ps[g][1][0], QB,
                       O, lsum);
    }
  }

#pragma unroll
  for (int qj = 0; qj < 2; qj++) {
    lsum[qj] += __shfl_xor(lsum[qj], 16);
    lsum[qj] += __shfl_xor(lsum[qj], 32);
  }

  int h = hkv * 4 + g;
#pragma unroll
  for (int qj = 0; qj < 2; qj++) {
    float invl[4];
#pragma unroll
    for (int r = 0; r < 4; r++) invl[r] = 1.f / __shfl(lsum[qj], quad * 4 + r);
#pragma unroll
    for (int nt = 0; nt < 4; nt++)
#pragma unroll
      for (int r = 0; r < 4; r++)
        Yb[((long)(b * Tq + q0 + qj * 16 + quad * 4 + r)) * 1024 + h * 64 +
           nt * 16 + l16] = f2bf(O[qj][nt][r] * invl[r]);
  }
}

// ---------------------------------------------------------------------------
extern "C" void kernel_launch(void* const* d_in, const int* in_sizes, int n_in,
                              void* d_out, int out_size, void* d_ws,
                              size_t ws_size, hipStream_t stream) {
  const float* x     = (const float*)d_in[0];
  const float* ve    = (const float*)d_in[1];
  const float* cosp  = (const float*)d_in[2];
  const float* sinp  = (const float*)d_in[3];
  const float* Wq    = (const float*)d_in[4];
  const float* Wk    = (const float*)d_in[5];
  const float* Wv    = (const float*)d_in[6];
  const float* Wproj = (const float*)d_in[7];
  const float* Wg    = (const float*)d_in[8];

  // workspace layout (~26.3 MB):
  //  [ 0        ,  8,388,608)  xb bf16     -> Yb bf16 (xb dead after qkv gemm)
  //  [ 8,388,608, 11,534,336)  WqkvT bf16
  //  [11,534,336, 13,631,488)  WprojT bf16
  //  [13,631,488, 22,020,096)  Qb bf16
  //  [22,020,096, 24,117,248)  Kb bf16
  //  [24,117,248, 26,214,400)  Vtb bf16
  //  [26,214,400, 26,279,936)  gate f32 [4096][4]
  char* base = (char*)d_ws;
  u16* xb      = (u16*)(base);
  u16* Yb      = xb;
  u16* WqkvT   = (u16*)(base + 8388608);
  u16* WprojT  = (u16*)(base + 11534336);
  u16* Qb      = (u16*)(base + 13631488);
  u16* Kb      = (u16*)(base + 22020096);
  u16* Vtb     = (u16*)(base + 24117248);
  float* gateb = (float*)(base + 26214400);
  float* out = (float*)d_out;

  prep<<<2752, 256, 0, stream>>>(x, xb, Wq, Wk, Wv, Wproj, Wg, WqkvT, WprojT,
                                 gateb);
  qkv_gemm_fused<<<dim3(12, 64), 256, 0, stream>>>(xb, WqkvT, ve, cosp, sinp,
                                                   gateb, Qb, Kb, Vtb);
  attn_mfma<<<512, 256, 0, stream>>>(Qb, Kb, Vtb, Yb);
  gemm_proj<<<dim3(8, 64), 256, 0, stream>>>(Yb, WprojT, out, 4096, 1024, 1024);
}